// Round 4
// baseline (300.251 us; speedup 1.0000x reference)
//
#include <hip/hip_runtime.h>
#include <hip/hip_bf16.h>
#include <cmath>

#define EPS 1e-5f

typedef __attribute__((ext_vector_type(8))) short bf16x8;
typedef __attribute__((ext_vector_type(4))) float f32x4;
typedef __attribute__((ext_vector_type(2))) float floatx2;

static __device__ __forceinline__ ushort f32_to_bf16(float f) {
    __hip_bfloat16 h = __float2bfloat16(f);
    return __builtin_bit_cast(ushort, h);
}
static __device__ __forceinline__ float blo(unsigned u) { return __uint_as_float(u << 16); }
static __device__ __forceinline__ float bhi(unsigned u) { return __uint_as_float(u & 0xffff0000u); }
static __device__ __forceinline__ unsigned bpack(float a, float b) {
    return (unsigned)f32_to_bf16(a) | ((unsigned)f32_to_bf16(b) << 16);
}
static __device__ __forceinline__ unsigned char f32_to_fp8(float v) {
    return (unsigned char)(__builtin_amdgcn_cvt_pk_fp8_f32(v, 0.f, 0, false) & 0xff);
}

static __device__ __forceinline__ void async16(const void* g, void* l) {
    __builtin_amdgcn_global_load_lds(
        (const __attribute__((address_space(1))) unsigned int*)g,
        (__attribute__((address_space(3))) unsigned int*)l, 16, 0, 0);
}

// decode 8 fp8 (uint2) -> accumulate into a0..a7
#define DEC8(u) { floatx2 p_; \
    p_ = __builtin_amdgcn_cvt_pk_f32_fp8((int)(u).x, false); a0 += p_.x; a1 += p_.y; \
    p_ = __builtin_amdgcn_cvt_pk_f32_fp8((int)(u).x, true);  a2 += p_.x; a3 += p_.y; \
    p_ = __builtin_amdgcn_cvt_pk_f32_fp8((int)(u).y, false); a4 += p_.x; a5 += p_.y; \
    p_ = __builtin_amdgcn_cvt_pk_f32_fp8((int)(u).y, true);  a6 += p_.x; a7 += p_.y; }
#define DEC4(u) { floatx2 p_; \
    p_ = __builtin_amdgcn_cvt_pk_f32_fp8((int)(u), false); a0 += p_.x; a1 += p_.y; \
    p_ = __builtin_amdgcn_cvt_pk_f32_fp8((int)(u), true);  a2 += p_.x; a3 += p_.y; }

// ---------------- prologue: bucket-count + x->bf16+fp8 + weight prep ----------------

__global__ void k_pre(const int* __restrict__ dst, int E, int* __restrict__ gcnt,
                      const float* __restrict__ x, ushort* __restrict__ cat1,
                      unsigned char* __restrict__ xq, int NX,
                      const float* __restrict__ w1l, const float* __restrict__ w1r,
                      const float* __restrict__ w2l, const float* __restrict__ w2r,
                      const float* __restrict__ w3l, const float* __restrict__ w3r,
                      ushort* __restrict__ Wt1, ushort* __restrict__ Wt2,
                      ushort* __restrict__ Wt3, int bktB, int cvtB) {
    int b = blockIdx.x;
    int t = threadIdx.x;
    if (b < bktB) {
        __shared__ int hist[256];
        hist[t] = 0;
        __syncthreads();
        int base = b * 8192;
        int end = base + 8192; if (end > E) end = E;
        for (int i = base + t; i < end; i += 256)
            atomicAdd(&hist[((unsigned)dst[i]) >> 8], 1);
        __syncthreads();
        if (hist[t]) atomicAdd(&gcnt[t], hist[t]);
    } else if (b < bktB + cvtB) {
        int i = (b - bktB) * 256 + t;
        if (i < NX) {
            int row = i >> 7, c = i & 127;
            float v = x[i];
            cat1[(size_t)row * 256 + 128 + c] = f32_to_bf16(v);
            xq[(size_t)row * 128 + c] = f32_to_fp8(v);
        }
    } else {
        int tt = (b - bktB - cvtB) * 256 + t;
        if (tt < 128 * 256) {
            int k = tt >> 8, c = tt & 255;
            Wt1[(size_t)c * 256 + k] = f32_to_bf16(w1l[tt]);
            Wt1[(size_t)c * 256 + 128 + k] = f32_to_bf16(w1r[tt]);
        }
        if (tt < 256 * 256) {
            int k = tt >> 8, c = tt & 255;
            Wt2[(size_t)c * 512 + k] = f32_to_bf16(w2l[tt]);
            Wt2[(size_t)c * 512 + 256 + k] = f32_to_bf16(w2r[tt]);
        }
        if (tt < 256 * 47) {
            int k = tt / 47, c = tt - k * 47;
            Wt3[(size_t)c * 256 + k] = f32_to_bf16(w3l[tt]);
            Wt3[(size_t)(64 + c) * 256 + k] = f32_to_bf16(w3r[tt]);
        }
    }
}

__global__ void k_bscan(const int* __restrict__ gcnt, int* __restrict__ gbase,
                        int* __restrict__ gtail, int NB) {
    __shared__ int s[256];
    int t = threadIdx.x;
    int v = (t < NB) ? gcnt[t] : 0;
    s[t] = v;
    __syncthreads();
    for (int off = 1; off < 256; off <<= 1) {
        int add = (t >= off) ? s[t - off] : 0;
        __syncthreads();
        s[t] += add;
        __syncthreads();
    }
    int excl = s[t] - v;
    if (t < NB) { gbase[t] = excl; gtail[t] = excl; }
}

__global__ void k_scatter(const int* __restrict__ src, const int* __restrict__ dst,
                          int E, int* __restrict__ gtail, uint2* __restrict__ pairs,
                          int NB) {
    __shared__ int hist[256];
    __shared__ int lcur[256];
    int t = threadIdx.x;
    hist[t] = 0;
    __syncthreads();
    int base = blockIdx.x * 8192;
    int end = base + 8192; if (end > E) end = E;
    for (int i = base + t; i < end; i += 256)
        atomicAdd(&hist[((unsigned)dst[i]) >> 8], 1);
    __syncthreads();
    if (t < NB && hist[t]) lcur[t] = atomicAdd(&gtail[t], hist[t]);
    __syncthreads();
    for (int i = base + t; i < end; i += 256) {
        int dd = dst[i];
        int pos = atomicAdd(&lcur[((unsigned)dd) >> 8], 1);
        pairs[pos] = make_uint2((unsigned)src[i], (unsigned)dd);
    }
}

__global__ void k_brow(const uint2* __restrict__ pairs, const int* __restrict__ gbase,
                       const int* __restrict__ gcnt, int* __restrict__ row_ptr,
                       float* __restrict__ inv_deg, int N, int E) {
    int b = blockIdx.x;
    __shared__ int hist[256];
    __shared__ int sc[256];
    int t = threadIdx.x;
    hist[t] = 0;
    __syncthreads();
    int s = gbase[b], cnt = gcnt[b];
    for (int i = t; i < cnt; i += 256) {
        uint2 p = pairs[s + i];
        atomicAdd(&hist[p.y & 255], 1);
    }
    __syncthreads();
    int d = hist[t];
    sc[t] = d;
    __syncthreads();
    for (int off = 1; off < 256; off <<= 1) {
        int add = (t >= off) ? sc[t - off] : 0;
        __syncthreads();
        sc[t] += add;
        __syncthreads();
    }
    int node = b * 256 + t;
    if (node < N) {
        row_ptr[node] = s + sc[t] - d;
        inv_deg[node] = 1.0f / (float)(d > 1 ? d : 1);
    }
    if (b == 0 && t == 0) row_ptr[N] = E;
}

__global__ void k_bfill(const uint2* __restrict__ pairs, const int* __restrict__ gbase,
                        const int* __restrict__ gcnt, const int* __restrict__ row_ptr,
                        int* __restrict__ colidx, int N) {
    int b = blockIdx.x;
    __shared__ int cur[256];
    int t = threadIdx.x;
    int node = b * 256 + t;
    cur[t] = (node < N) ? row_ptr[node] : 0;
    __syncthreads();
    int s = gbase[b], cnt = gcnt[b];
    for (int i = t; i < cnt; i += 256) {
        uint2 p = pairs[s + i];
        int pos = atomicAdd(&cur[p.y & 255], 1);
        colidx[pos] = (int)p.x;
    }
}

// ---------------- fp8 aggregation: wave per node, 4-deep ILP ----------------

__global__ void k_agg256q(const unsigned char* __restrict__ hq, const int* __restrict__ rp,
                          const int* __restrict__ ci, const float* __restrict__ inv_deg,
                          ushort* __restrict__ out, int ldo, int N) {
    int wid = (blockIdx.x * blockDim.x + threadIdx.x) >> 6;
    int lane = threadIdx.x & 63;
    if (wid >= N) return;
    int s = rp[wid], e = rp[wid + 1];
    int half = lane >> 5, l32 = lane & 31;
    int cnt = e - s;
    int n_my = (cnt - half + 1) >> 1;
    int i = s + half;
    float a0 = 0, a1 = 0, a2 = 0, a3 = 0, a4 = 0, a5 = 0, a6 = 0, a7 = 0;
    size_t lo = (size_t)l32 * 8;
    while (n_my >= 4) {
        int c0 = ci[i], c1 = ci[i + 2], c2 = ci[i + 4], c3 = ci[i + 6];
        uint2 u0 = *reinterpret_cast<const uint2*>(hq + (size_t)c0 * 256 + lo);
        uint2 u1 = *reinterpret_cast<const uint2*>(hq + (size_t)c1 * 256 + lo);
        uint2 u2 = *reinterpret_cast<const uint2*>(hq + (size_t)c2 * 256 + lo);
        uint2 u3 = *reinterpret_cast<const uint2*>(hq + (size_t)c3 * 256 + lo);
        DEC8(u0); DEC8(u1); DEC8(u2); DEC8(u3);
        i += 8; n_my -= 4;
    }
    while (n_my > 0) {
        int c = ci[i];
        uint2 u = *reinterpret_cast<const uint2*>(hq + (size_t)c * 256 + lo);
        DEC8(u);
        i += 2; n_my--;
    }
    a0 += __shfl_xor(a0, 32, 64); a1 += __shfl_xor(a1, 32, 64);
    a2 += __shfl_xor(a2, 32, 64); a3 += __shfl_xor(a3, 32, 64);
    a4 += __shfl_xor(a4, 32, 64); a5 += __shfl_xor(a5, 32, 64);
    a6 += __shfl_xor(a6, 32, 64); a7 += __shfl_xor(a7, 32, 64);
    if (half == 0) {
        float id = inv_deg[wid];
        uint4 o;
        o.x = bpack(a0 * id, a1 * id); o.y = bpack(a2 * id, a3 * id);
        o.z = bpack(a4 * id, a5 * id); o.w = bpack(a6 * id, a7 * id);
        *reinterpret_cast<uint4*>(out + (size_t)wid * ldo + l32 * 8) = o;
    }
}

__global__ void k_agg128q(const unsigned char* __restrict__ hq, const int* __restrict__ rp,
                          const int* __restrict__ ci, const float* __restrict__ inv_deg,
                          ushort* __restrict__ out, int ldo, int N) {
    int wid = (blockIdx.x * blockDim.x + threadIdx.x) >> 6;
    int lane = threadIdx.x & 63;
    if (wid >= N) return;
    int s = rp[wid], e = rp[wid + 1];
    int g = lane >> 4, l16 = lane & 15;
    int cnt = e - s;
    int n_my = (cnt - g + 3) >> 2;
    int i = s + g;
    float a0 = 0, a1 = 0, a2 = 0, a3 = 0, a4 = 0, a5 = 0, a6 = 0, a7 = 0;
    size_t lo = (size_t)l16 * 8;
    while (n_my >= 4) {
        int c0 = ci[i], c1 = ci[i + 4], c2 = ci[i + 8], c3 = ci[i + 12];
        uint2 u0 = *reinterpret_cast<const uint2*>(hq + (size_t)c0 * 128 + lo);
        uint2 u1 = *reinterpret_cast<const uint2*>(hq + (size_t)c1 * 128 + lo);
        uint2 u2 = *reinterpret_cast<const uint2*>(hq + (size_t)c2 * 128 + lo);
        uint2 u3 = *reinterpret_cast<const uint2*>(hq + (size_t)c3 * 128 + lo);
        DEC8(u0); DEC8(u1); DEC8(u2); DEC8(u3);
        i += 16; n_my -= 4;
    }
    while (n_my > 0) {
        int c = ci[i];
        uint2 u = *reinterpret_cast<const uint2*>(hq + (size_t)c * 128 + lo);
        DEC8(u);
        i += 4; n_my--;
    }
#pragma unroll
    for (int off = 16; off <= 32; off <<= 1) {
        a0 += __shfl_xor(a0, off, 64); a1 += __shfl_xor(a1, off, 64);
        a2 += __shfl_xor(a2, off, 64); a3 += __shfl_xor(a3, off, 64);
        a4 += __shfl_xor(a4, off, 64); a5 += __shfl_xor(a5, off, 64);
        a6 += __shfl_xor(a6, off, 64); a7 += __shfl_xor(a7, off, 64);
    }
    if (lane < 16) {
        float id = inv_deg[wid];
        uint4 o;
        o.x = bpack(a0 * id, a1 * id); o.y = bpack(a2 * id, a3 * id);
        o.z = bpack(a4 * id, a5 * id); o.w = bpack(a6 * id, a7 * id);
        *reinterpret_cast<uint4*>(out + (size_t)wid * ldo + l16 * 8) = o;
    }
}

__global__ void k_agg47fq(const unsigned char* __restrict__ p3q, const int* __restrict__ rp,
                          const int* __restrict__ ci, const float* __restrict__ inv_deg,
                          const float* __restrict__ q3, float* __restrict__ out,
                          int N, int OUTD) {
    int wid = (blockIdx.x * blockDim.x + threadIdx.x) >> 6;
    int lane = threadIdx.x & 63;
    if (wid >= N) return;
    int s = rp[wid], e = rp[wid + 1];
    int g = lane >> 4, l16 = lane & 15;
    int cnt = e - s;
    int n_my = (cnt - g + 3) >> 2;
    int i = s + g;
    float a0 = 0, a1 = 0, a2 = 0, a3 = 0;
    size_t lo = (size_t)l16 * 4;
    while (n_my >= 4) {
        int c0 = ci[i], c1 = ci[i + 4], c2 = ci[i + 8], c3 = ci[i + 12];
        unsigned u0 = *reinterpret_cast<const unsigned*>(p3q + (size_t)c0 * 64 + lo);
        unsigned u1 = *reinterpret_cast<const unsigned*>(p3q + (size_t)c1 * 64 + lo);
        unsigned u2 = *reinterpret_cast<const unsigned*>(p3q + (size_t)c2 * 64 + lo);
        unsigned u3 = *reinterpret_cast<const unsigned*>(p3q + (size_t)c3 * 64 + lo);
        DEC4(u0); DEC4(u1); DEC4(u2); DEC4(u3);
        i += 16; n_my -= 4;
    }
    while (n_my > 0) {
        int c = ci[i];
        unsigned u = *reinterpret_cast<const unsigned*>(p3q + (size_t)c * 64 + lo);
        DEC4(u);
        i += 4; n_my--;
    }
#pragma unroll
    for (int off = 16; off <= 32; off <<= 1) {
        a0 += __shfl_xor(a0, off, 64); a1 += __shfl_xor(a1, off, 64);
        a2 += __shfl_xor(a2, off, 64); a3 += __shfl_xor(a3, off, 64);
    }
    float id = inv_deg[wid];
    int c0 = l16 * 4;
    float z0 = (c0 + 0 < OUTD) ? a0 * id + q3[(size_t)wid * 48 + c0 + 0] : -INFINITY;
    float z1 = (c0 + 1 < OUTD) ? a1 * id + q3[(size_t)wid * 48 + c0 + 1] : -INFINITY;
    float z2 = (c0 + 2 < OUTD) ? a2 * id + q3[(size_t)wid * 48 + c0 + 2] : -INFINITY;
    float z3 = (c0 + 3 < OUTD) ? a3 * id + q3[(size_t)wid * 48 + c0 + 3] : -INFINITY;
    float m = fmaxf(fmaxf(z0, z1), fmaxf(z2, z3));
#pragma unroll
    for (int off = 1; off <= 8; off <<= 1) m = fmaxf(m, __shfl_xor(m, off, 64));
    float es = ((c0 + 0 < OUTD) ? __expf(z0 - m) : 0.f) + ((c0 + 1 < OUTD) ? __expf(z1 - m) : 0.f)
             + ((c0 + 2 < OUTD) ? __expf(z2 - m) : 0.f) + ((c0 + 3 < OUTD) ? __expf(z3 - m) : 0.f);
#pragma unroll
    for (int off = 1; off <= 8; off <<= 1) es += __shfl_xor(es, off, 64);
    float ls = __logf(es) + m;
    if (lane < 16) {
        if (c0 + 0 < OUTD) out[(size_t)wid * OUTD + c0 + 0] = z0 - ls;
        if (c0 + 1 < OUTD) out[(size_t)wid * OUTD + c0 + 1] = z1 - ls;
        if (c0 + 2 < OUTD) out[(size_t)wid * OUTD + c0 + 2] = z2 - ls;
        if (c0 + 3 < OUTD) out[(size_t)wid * OUTD + c0 + 3] = z3 - ls;
    }
}

// ---------------- bf16 MFMA GEMM, 64x128 tile, DEPTH-4 circular pipeline ----
// Little's-law fix: per k-step each block keeps TILES t+1,t+2 in flight
// (24KB) instead of 1 tile (12KB). Single barrier per k-step (safe at
// DEPTH>=3: stage into buf (t+3)&3=(t-1)&3 whose readers passed this
// barrier). vmcnt counted, never drained mid-loop. LDS 52KB -> 3 blocks/CU.
// EPI=2: bf16 z + per-block psum[bx*256+col]. EPI=1: p3q fp8 + q3 f32.

template <int EPI>
__global__ __launch_bounds__(256) void k_mgemm(
    const ushort* __restrict__ A, const ushort* __restrict__ Wt,
    const float* __restrict__ bias, ushort* __restrict__ outb,
    unsigned char* __restrict__ outq,
    float* __restrict__ q3, float* __restrict__ psum, float* __restrict__ psq,
    int Nrows, int K, int M) {
    __shared__ __align__(16) ushort sA[4][64 * 32];
    __shared__ __align__(16) ushort sB[4][128 * 32];
    __shared__ float red[2][2][4][16][2];
    const int tid = threadIdx.x;
    const int w = tid >> 6, l = tid & 63;
    const int wr = w >> 1, wc = w & 1;
    const int row0 = blockIdx.x * 64, col0 = blockIdx.y * 128;
    const int li = l & 15, kg = l >> 4;

    // staging addresses (k-invariant)
    const int rA = tid >> 2, kgpA = tid & 3;
    const int kglA = (kgpA - (rA >> 1)) & 3;
    int grA = row0 + rA; if (grA >= Nrows) grA = Nrows - 1;
    const ushort* gpA = A + (size_t)grA * K + kglA * 8;

    const int rB0 = tid >> 2, kglB0 = ((tid & 3) - (rB0 >> 1)) & 3;
    const ushort* gpB0 = Wt + (size_t)(col0 + rB0) * K + kglB0 * 8;
    const int cB1 = tid + 256;
    const int rB1 = cB1 >> 2, kglB1 = ((cB1 & 3) - (rB1 >> 1)) & 3;
    const ushort* gpB1 = Wt + (size_t)(col0 + rB1) * K + kglB1 * 8;

    const int nk = K >> 5;

    auto stageT = [&](int t) {
        const int kt = t << 5;
        const int buf = t & 3;
        async16(gpA + kt, &sA[buf][(size_t)tid * 8]);
        async16(gpB0 + kt, &sB[buf][(size_t)tid * 8]);
        async16(gpB1 + kt, &sB[buf][(size_t)cB1 * 8]);
    };

    // prologue: stage tiles 0..2
    stageT(0);
    if (nk > 1) stageT(1);
    if (nk > 2) stageT(2);

    f32x4 acc[2][4] = {};

    for (int t = 0; t < nk; ++t) {
        // tiles still wanted in flight after this wait:
        int rem = ((t + 3 < nk) ? t + 3 : nk) - (t + 1);
        if (rem == 2)      asm volatile("s_waitcnt vmcnt(6)" ::: "memory");
        else if (rem == 1) asm volatile("s_waitcnt vmcnt(3)" ::: "memory");
        else               asm volatile("s_waitcnt vmcnt(0)" ::: "memory");
        __builtin_amdgcn_s_barrier();          // tile t resident for all waves
        __builtin_amdgcn_sched_barrier(0);     // don't hoist ds_reads above

        if (t + 3 < nk) stageT(t + 3);         // overlaps with compute below

        const int buf = t & 3;
        bf16x8 af[2], bfr[4];
#pragma unroll
        for (int m = 0; m < 2; m++) {
            int r = wr * 32 + m * 16 + li;
            af[m] = *reinterpret_cast<const bf16x8*>(&sA[buf][(r * 4 + ((kg + (r >> 1)) & 3)) * 8]);
        }
#pragma unroll
        for (int n = 0; n < 4; n++) {
            int r = wc * 64 + n * 16 + li;
            bfr[n] = *reinterpret_cast<const bf16x8*>(&sB[buf][(r * 4 + ((kg + (r >> 1)) & 3)) * 8]);
        }
#pragma unroll
        for (int m = 0; m < 2; m++)
#pragma unroll
            for (int n = 0; n < 4; n++)
                acc[m][n] = __builtin_amdgcn_mfma_f32_16x16x32_bf16(af[m], bfr[n], acc[m][n], 0, 0, 0);
        __builtin_amdgcn_sched_barrier(0);
    }

    if constexpr (EPI == 2) {
#pragma unroll
        for (int n = 0; n < 4; n++) {
            int col = col0 + wc * 64 + n * 16 + li;
            float b = bias[col];
            float s = 0.f, sq = 0.f;
#pragma unroll
            for (int m = 0; m < 2; m++) {
                int rbase = row0 + wr * 32 + m * 16 + kg * 4;
#pragma unroll
                for (int qi = 0; qi < 4; qi++) {
                    int row = rbase + qi;
                    if (row < Nrows) {
                        float v = acc[m][n][qi] + b;
                        outb[(size_t)row * M + col] = f32_to_bf16(v);
                        s += v; sq += v * v;
                    }
                }
            }
            s += __shfl_xor(s, 16, 64); s += __shfl_xor(s, 32, 64);
            sq += __shfl_xor(sq, 16, 64); sq += __shfl_xor(sq, 32, 64);
            if (kg == 0) { red[wr][wc][n][li][0] = s; red[wr][wc][n][li][1] = sq; }
        }
        __syncthreads();
        if (wr == 0 && kg == 0) {
#pragma unroll
            for (int n = 0; n < 4; n++) {
                int gcol = col0 + wc * 64 + n * 16 + li;
                psum[(size_t)blockIdx.x * 256 + gcol] = red[0][wc][n][li][0] + red[1][wc][n][li][0];
                psq[(size_t)blockIdx.x * 256 + gcol] = red[0][wc][n][li][1] + red[1][wc][n][li][1];
            }
        }
    } else {
#pragma unroll
        for (int n = 0; n < 4; n++) {
            int col = wc * 64 + n * 16 + li;
#pragma unroll
            for (int m = 0; m < 2; m++) {
                int rbase = row0 + wr * 32 + m * 16 + kg * 4;
#pragma unroll
                for (int qi = 0; qi < 4; qi++) {
                    int row = rbase + qi;
                    if (row >= Nrows) continue;
                    float v = acc[m][n][qi];
                    if (wc == 0) {
                        outq[(size_t)row * 64 + col] = f32_to_fp8(col < 47 ? v : 0.f);
                    } else {
                        int qc = col - 64;
                        if (qc < 47) q3[(size_t)row * 48 + qc] = v + bias[qc];
                    }
                }
            }
        }
    }
}

// ---------------- BN finalize + apply ----------------

__global__ void k_bn_final(const float* __restrict__ psum, const float* __restrict__ psq,
                           int nb, int N, const float* __restrict__ g,
                           const float* __restrict__ be, float* __restrict__ scale,
                           float* __restrict__ shift) {
    int c = blockIdx.x;
    int t = threadIdx.x;
    float s = 0.f, q = 0.f;
    for (int b = t; b < nb; b += 256) { s += psum[(size_t)b * 256 + c]; q += psq[(size_t)b * 256 + c]; }
#pragma unroll
    for (int off = 32; off; off >>= 1) { s += __shfl_xor(s, off, 64); q += __shfl_xor(q, off, 64); }
    __shared__ float ls[4], lq[4];
    int wv = t >> 6;
    if ((t & 63) == 0) { ls[wv] = s; lq[wv] = q; }
    __syncthreads();
    if (t == 0) {
        s = ls[0] + ls[1] + ls[2] + ls[3];
        q = lq[0] + lq[1] + lq[2] + lq[3];
        float mu = s / (float)N;
        float var = q / (float)N - mu * mu;
        float sc = g[c] * rsqrtf(var + EPS);
        scale[c] = sc;
        shift[c] = be[c] - mu * sc;
    }
}

__global__ void k_bn_apply_b(const ushort* __restrict__ zb, long total8,
                             const float* __restrict__ scale, const float* __restrict__ shift,
                             ushort* __restrict__ outb, int ldo, int off,
                             unsigned char* __restrict__ hq) {
    long i = blockIdx.x * (long)blockDim.x + threadIdx.x;
    long stride = (long)gridDim.x * blockDim.x;
    for (; i < total8; i += stride) {
        long idx = i * 8;
        int row = (int)(idx >> 8);
        int c = (int)(idx & 255);
        uint4 u = *reinterpret_cast<const uint4*>(zb + idx);
        float y0 = fmaxf(blo(u.x) * scale[c + 0] + shift[c + 0], 0.f);
        float y1 = fmaxf(bhi(u.x) * scale[c + 1] + shift[c + 1], 0.f);
        float y2 = fmaxf(blo(u.y) * scale[c + 2] + shift[c + 2], 0.f);
        float y3 = fmaxf(bhi(u.y) * scale[c + 3] + shift[c + 3], 0.f);
        float y4 = fmaxf(blo(u.z) * scale[c + 4] + shift[c + 4], 0.f);
        float y5 = fmaxf(bhi(u.z) * scale[c + 5] + shift[c + 5], 0.f);
        float y6 = fmaxf(blo(u.w) * scale[c + 6] + shift[c + 6], 0.f);
        float y7 = fmaxf(bhi(u.w) * scale[c + 7] + shift[c + 7], 0.f);
        uint4 o;
        o.x = bpack(y0, y1); o.y = bpack(y2, y3); o.z = bpack(y4, y5); o.w = bpack(y6, y7);
        *reinterpret_cast<uint4*>(outb + (size_t)row * ldo + off + c) = o;
        if (hq) {
            unsigned lo8 = 0, hi8 = 0;
            lo8 = (unsigned)__builtin_amdgcn_cvt_pk_fp8_f32(y0, y1, 0, false);
            lo8 = (unsigned)__builtin_amdgcn_cvt_pk_fp8_f32(y2, y3, (int)lo8, true);
            hi8 = (unsigned)__builtin_amdgcn_cvt_pk_fp8_f32(y4, y5, 0, false);
            hi8 = (unsigned)__builtin_amdgcn_cvt_pk_fp8_f32(y6, y7, (int)hi8, true);
            *reinterpret_cast<uint2*>(hq + (size_t)row * 256 + c) = make_uint2(lo8, hi8);
        }
    }
}

// ---------------- host ----------------

extern "C" void kernel_launch(void* const* d_in, const int* in_sizes, int n_in,
                              void* d_out, int out_size, void* d_ws, size_t ws_size,
                              hipStream_t stream) {
    const float* x   = (const float*)d_in[0];
    const int*   ei  = (const int*)d_in[1];
    const float* w1l = (const float*)d_in[2];
    const float* w1r = (const float*)d_in[3];
    const float* b1  = (const float*)d_in[4];
    const float* g1  = (const float*)d_in[5];
    const float* be1 = (const float*)d_in[6];
    const float* w2l = (const float*)d_in[7];
    const float* w2r = (const float*)d_in[8];
    const float* b2  = (const float*)d_in[9];
    const float* g2  = (const float*)d_in[10];
    const float* be2 = (const float*)d_in[11];
    const float* w3l = (const float*)d_in[12];
    const float* w3r = (const float*)d_in[13];
    const float* b3  = (const float*)d_in[14];
    float* out = (float*)d_out;

    const int INDIM = 128, HID = 256;
    int N = in_sizes[0] / INDIM;
    int E = in_sizes[1] / 2;
    int OUTD = in_sizes[14];
    const int* src = ei;
    const int* dst = ei + E;
    int NB = (N + 255) >> 8;

    size_t off = 0;
    auto carve = [&](size_t bytes) -> char* {
        char* p = (char*)d_ws + off;
        off = (off + bytes + 255) & ~(size_t)255;
        return p;
    };
    int*    row_ptr  = (int*)carve((size_t)(N + 1) * 4);
    float*  inv_deg  = (float*)carve((size_t)N * 4);
    int*    gcnt     = (int*)carve(256 * 4);
    int*    gbase    = (int*)carve(256 * 4);
    int*    gtail    = (int*)carve(256 * 4);
    uint2*  pairs    = (uint2*)carve((size_t)E * 8);
    int*    colidx   = (int*)carve((size_t)E * 4);
    float*  psum     = (float*)carve((size_t)256 * 1024 * 4);
    float*  psq      = (float*)carve((size_t)256 * 1024 * 4);
    float*  bnscale  = (float*)carve(256 * 4);
    float*  bnshift  = (float*)carve(256 * 4);
    ushort* Wt1      = (ushort*)carve((size_t)256 * 256 * 2);
    ushort* Wt2      = (ushort*)carve((size_t)256 * 512 * 2);
    ushort* Wt3      = (ushort*)carve((size_t)128 * 256 * 2);
    ushort* cat1     = (ushort*)carve((size_t)N * 256 * 2);   // [agg(x)|xb] bf16
    unsigned char* xq  = (unsigned char*)carve((size_t)N * 128);  // x fp8
    unsigned char* h1q = (unsigned char*)carve((size_t)N * 256);  // h1 fp8
    ushort* cat2     = (ushort*)carve((size_t)N * 512 * 2);   // [agg(h1)|h1]; later h2b
    ushort* zb       = (ushort*)carve((size_t)N * HID * 2);   // bf16 z1/z2
    unsigned char* p3q = (unsigned char*)carve((size_t)N * 64);   // p3 fp8
    float*  q3       = (float*)carve((size_t)N * 48 * 4);
    (void)ws_size; (void)n_in; (void)out_size;

    hipMemsetAsync(gcnt, 0, 256 * 4, stream);
    hipMemsetAsync(Wt3, 0, (size_t)128 * 256 * 2, stream);

    int bktB = (E + 8191) / 8192;
    int cvtB = (N * 128 + 255) / 256;
    k_pre<<<bktB + cvtB + 256, 256, 0, stream>>>(dst, E, gcnt, x, cat1, xq, N * 128,
                                                 w1l, w1r, w2l, w2r, w3l, w3r,
                                                 Wt1, Wt2, Wt3, bktB, cvtB);
    k_bscan<<<1, 256, 0, stream>>>(gcnt, gbase, gtail, NB);
    k_scatter<<<bktB, 256, 0, stream>>>(src, dst, E, gtail, pairs, NB);
    k_brow<<<NB, 256, 0, stream>>>(pairs, gbase, gcnt, row_ptr, inv_deg, N, E);
    k_bfill<<<NB, 256, 0, stream>>>(pairs, gbase, gcnt, row_ptr, colidx, N);

    int aggBlocks = (N + 3) / 4;
    int MB = (N + 63) / 64;   // 64-row tiles
    long total8 = (long)N * 32;
    ushort* h2b = cat2;  // reuse

    // ---- layer 1 ----
    k_agg128q<<<aggBlocks, 256, 0, stream>>>(xq, row_ptr, colidx, inv_deg, cat1, 256, N);
    k_mgemm<2><<<dim3(MB, 2), 256, 0, stream>>>(cat1, Wt1, b1, zb, nullptr, nullptr,
                                                psum, psq, N, 256, 256);
    k_bn_final<<<256, 256, 0, stream>>>(psum, psq, MB, N, g1, be1, bnscale, bnshift);
    k_bn_apply_b<<<1024, 256, 0, stream>>>(zb, total8, bnscale, bnshift, cat2, 512, 256, h1q);

    // ---- layer 2 ----
    k_agg256q<<<aggBlocks, 256, 0, stream>>>(h1q, row_ptr, colidx, inv_deg, cat2, 512, N);
    k_mgemm<2><<<dim3(MB, 2), 256, 0, stream>>>(cat2, Wt2, b2, zb, nullptr, nullptr,
                                                psum, psq, N, 512, 256);
    k_bn_final<<<256, 256, 0, stream>>>(psum, psq, MB, N, g2, be2, bnscale, bnshift);
    k_bn_apply_b<<<1024, 256, 0, stream>>>(zb, total8, bnscale, bnshift, h2b, 256, 0, nullptr);

    // ---- layer 3: fp8 p3 / f32 q3 epilogue, then fused agg + log_softmax ----
    k_mgemm<1><<<dim3(MB, 1), 256, 0, stream>>>(h2b, Wt3, b3, nullptr, p3q, q3,
                                                nullptr, nullptr, N, 256, 128);
    k_agg47fq<<<aggBlocks, 256, 0, stream>>>(p3q, row_ptr, colidx, inv_deg, q3, out, N, OUTD);
}

// Round 5
// 296.143 us; speedup vs baseline: 1.0139x; 1.0139x over previous
//
#include <hip/hip_runtime.h>
#include <hip/hip_bf16.h>
#include <cmath>

#define EPS 1e-5f

typedef __attribute__((ext_vector_type(8))) short bf16x8;
typedef __attribute__((ext_vector_type(4))) float f32x4;
typedef __attribute__((ext_vector_type(2))) float floatx2;

static __device__ __forceinline__ ushort f32_to_bf16(float f) {
    __hip_bfloat16 h = __float2bfloat16(f);
    return __builtin_bit_cast(ushort, h);
}
static __device__ __forceinline__ float blo(unsigned u) { return __uint_as_float(u << 16); }
static __device__ __forceinline__ float bhi(unsigned u) { return __uint_as_float(u & 0xffff0000u); }
static __device__ __forceinline__ unsigned bpack(float a, float b) {
    return (unsigned)f32_to_bf16(a) | ((unsigned)f32_to_bf16(b) << 16);
}
static __device__ __forceinline__ unsigned char f32_to_fp8(float v) {
    return (unsigned char)(__builtin_amdgcn_cvt_pk_fp8_f32(v, 0.f, 0, false) & 0xff);
}

static __device__ __forceinline__ void async16(const void* g, void* l) {
    __builtin_amdgcn_global_load_lds(
        (const __attribute__((address_space(1))) unsigned int*)g,
        (__attribute__((address_space(3))) unsigned int*)l, 16, 0, 0);
}

// decode 8 fp8 (uint2) -> accumulate into a0..a7
#define DEC8(u) { floatx2 p_; \
    p_ = __builtin_amdgcn_cvt_pk_f32_fp8((int)(u).x, false); a0 += p_.x; a1 += p_.y; \
    p_ = __builtin_amdgcn_cvt_pk_f32_fp8((int)(u).x, true);  a2 += p_.x; a3 += p_.y; \
    p_ = __builtin_amdgcn_cvt_pk_f32_fp8((int)(u).y, false); a4 += p_.x; a5 += p_.y; \
    p_ = __builtin_amdgcn_cvt_pk_f32_fp8((int)(u).y, true);  a6 += p_.x; a7 += p_.y; }
#define DEC4(u) { floatx2 p_; \
    p_ = __builtin_amdgcn_cvt_pk_f32_fp8((int)(u), false); a0 += p_.x; a1 += p_.y; \
    p_ = __builtin_amdgcn_cvt_pk_f32_fp8((int)(u), true);  a2 += p_.x; a3 += p_.y; }

// ---------------- prologue: bucket-count + x->bf16+fp8 + weight prep ----------------

__global__ void k_pre(const int* __restrict__ dst, int E, int* __restrict__ gcnt,
                      const float* __restrict__ x, ushort* __restrict__ cat1,
                      unsigned char* __restrict__ xq, int NX,
                      const float* __restrict__ w1l, const float* __restrict__ w1r,
                      const float* __restrict__ w2l, const float* __restrict__ w2r,
                      const float* __restrict__ w3l, const float* __restrict__ w3r,
                      ushort* __restrict__ Wt1, ushort* __restrict__ Wt2,
                      ushort* __restrict__ Wt3, int bktB, int cvtB) {
    int b = blockIdx.x;
    int t = threadIdx.x;
    if (b < bktB) {
        __shared__ int hist[256];
        hist[t] = 0;
        __syncthreads();
        int base = b * 8192;
        int end = base + 8192; if (end > E) end = E;
        for (int i = base + t; i < end; i += 256)
            atomicAdd(&hist[((unsigned)dst[i]) >> 8], 1);
        __syncthreads();
        if (hist[t]) atomicAdd(&gcnt[t], hist[t]);
    } else if (b < bktB + cvtB) {
        int i = (b - bktB) * 256 + t;
        if (i < NX) {
            int row = i >> 7, c = i & 127;
            float v = x[i];
            cat1[(size_t)row * 256 + 128 + c] = f32_to_bf16(v);
            xq[(size_t)row * 128 + c] = f32_to_fp8(v);
        }
    } else {
        int tt = (b - bktB - cvtB) * 256 + t;
        if (tt < 128 * 256) {
            int k = tt >> 8, c = tt & 255;
            Wt1[(size_t)c * 256 + k] = f32_to_bf16(w1l[tt]);
            Wt1[(size_t)c * 256 + 128 + k] = f32_to_bf16(w1r[tt]);
        }
        if (tt < 256 * 256) {
            int k = tt >> 8, c = tt & 255;
            Wt2[(size_t)c * 512 + k] = f32_to_bf16(w2l[tt]);
            Wt2[(size_t)c * 512 + 256 + k] = f32_to_bf16(w2r[tt]);
        }
        if (tt < 256 * 47) {
            int k = tt / 47, c = tt - k * 47;
            Wt3[(size_t)c * 256 + k] = f32_to_bf16(w3l[tt]);
            Wt3[(size_t)(64 + c) * 256 + k] = f32_to_bf16(w3r[tt]);
        }
    }
}

__global__ void k_bscan(const int* __restrict__ gcnt, int* __restrict__ gbase,
                        int* __restrict__ gtail, int NB) {
    __shared__ int s[256];
    int t = threadIdx.x;
    int v = (t < NB) ? gcnt[t] : 0;
    s[t] = v;
    __syncthreads();
    for (int off = 1; off < 256; off <<= 1) {
        int add = (t >= off) ? s[t - off] : 0;
        __syncthreads();
        s[t] += add;
        __syncthreads();
    }
    int excl = s[t] - v;
    if (t < NB) { gbase[t] = excl; gtail[t] = excl; }
}

__global__ void k_scatter(const int* __restrict__ src, const int* __restrict__ dst,
                          int E, int* __restrict__ gtail, uint2* __restrict__ pairs,
                          int NB) {
    __shared__ int hist[256];
    __shared__ int lcur[256];
    int t = threadIdx.x;
    hist[t] = 0;
    __syncthreads();
    int base = blockIdx.x * 8192;
    int end = base + 8192; if (end > E) end = E;
    for (int i = base + t; i < end; i += 256)
        atomicAdd(&hist[((unsigned)dst[i]) >> 8], 1);
    __syncthreads();
    if (t < NB && hist[t]) lcur[t] = atomicAdd(&gtail[t], hist[t]);
    __syncthreads();
    for (int i = base + t; i < end; i += 256) {
        int dd = dst[i];
        int pos = atomicAdd(&lcur[((unsigned)dd) >> 8], 1);
        pairs[pos] = make_uint2((unsigned)src[i], (unsigned)dd);
    }
}

__global__ void k_brow(const uint2* __restrict__ pairs, const int* __restrict__ gbase,
                       const int* __restrict__ gcnt, int* __restrict__ row_ptr,
                       float* __restrict__ inv_deg, int N, int E) {
    int b = blockIdx.x;
    __shared__ int hist[256];
    __shared__ int sc[256];
    int t = threadIdx.x;
    hist[t] = 0;
    __syncthreads();
    int s = gbase[b], cnt = gcnt[b];
    for (int i = t; i < cnt; i += 256) {
        uint2 p = pairs[s + i];
        atomicAdd(&hist[p.y & 255], 1);
    }
    __syncthreads();
    int d = hist[t];
    sc[t] = d;
    __syncthreads();
    for (int off = 1; off < 256; off <<= 1) {
        int add = (t >= off) ? sc[t - off] : 0;
        __syncthreads();
        sc[t] += add;
        __syncthreads();
    }
    int node = b * 256 + t;
    if (node < N) {
        row_ptr[node] = s + sc[t] - d;
        inv_deg[node] = 1.0f / (float)(d > 1 ? d : 1);
    }
    if (b == 0 && t == 0) row_ptr[N] = E;
}

__global__ void k_bfill(const uint2* __restrict__ pairs, const int* __restrict__ gbase,
                        const int* __restrict__ gcnt, const int* __restrict__ row_ptr,
                        int* __restrict__ colidx, int N) {
    int b = blockIdx.x;
    __shared__ int cur[256];
    int t = threadIdx.x;
    int node = b * 256 + t;
    cur[t] = (node < N) ? row_ptr[node] : 0;
    __syncthreads();
    int s = gbase[b], cnt = gcnt[b];
    for (int i = t; i < cnt; i += 256) {
        uint2 p = pairs[s + i];
        int pos = atomicAdd(&cur[p.y & 255], 1);
        colidx[pos] = (int)p.x;
    }
}

// ---------------- fp8 aggregation: wave per node, 4-deep ILP ----------------

__global__ void k_agg256q(const unsigned char* __restrict__ hq, const int* __restrict__ rp,
                          const int* __restrict__ ci, const float* __restrict__ inv_deg,
                          ushort* __restrict__ out, int ldo, int N) {
    int wid = (blockIdx.x * blockDim.x + threadIdx.x) >> 6;
    int lane = threadIdx.x & 63;
    if (wid >= N) return;
    int s = rp[wid], e = rp[wid + 1];
    int half = lane >> 5, l32 = lane & 31;
    int cnt = e - s;
    int n_my = (cnt - half + 1) >> 1;
    int i = s + half;
    float a0 = 0, a1 = 0, a2 = 0, a3 = 0, a4 = 0, a5 = 0, a6 = 0, a7 = 0;
    size_t lo = (size_t)l32 * 8;
    while (n_my >= 4) {
        int c0 = ci[i], c1 = ci[i + 2], c2 = ci[i + 4], c3 = ci[i + 6];
        uint2 u0 = *reinterpret_cast<const uint2*>(hq + (size_t)c0 * 256 + lo);
        uint2 u1 = *reinterpret_cast<const uint2*>(hq + (size_t)c1 * 256 + lo);
        uint2 u2 = *reinterpret_cast<const uint2*>(hq + (size_t)c2 * 256 + lo);
        uint2 u3 = *reinterpret_cast<const uint2*>(hq + (size_t)c3 * 256 + lo);
        DEC8(u0); DEC8(u1); DEC8(u2); DEC8(u3);
        i += 8; n_my -= 4;
    }
    while (n_my > 0) {
        int c = ci[i];
        uint2 u = *reinterpret_cast<const uint2*>(hq + (size_t)c * 256 + lo);
        DEC8(u);
        i += 2; n_my--;
    }
    a0 += __shfl_xor(a0, 32, 64); a1 += __shfl_xor(a1, 32, 64);
    a2 += __shfl_xor(a2, 32, 64); a3 += __shfl_xor(a3, 32, 64);
    a4 += __shfl_xor(a4, 32, 64); a5 += __shfl_xor(a5, 32, 64);
    a6 += __shfl_xor(a6, 32, 64); a7 += __shfl_xor(a7, 32, 64);
    if (half == 0) {
        float id = inv_deg[wid];
        uint4 o;
        o.x = bpack(a0 * id, a1 * id); o.y = bpack(a2 * id, a3 * id);
        o.z = bpack(a4 * id, a5 * id); o.w = bpack(a6 * id, a7 * id);
        *reinterpret_cast<uint4*>(out + (size_t)wid * ldo + l32 * 8) = o;
    }
}

__global__ void k_agg128q(const unsigned char* __restrict__ hq, const int* __restrict__ rp,
                          const int* __restrict__ ci, const float* __restrict__ inv_deg,
                          ushort* __restrict__ out, int ldo, int N) {
    int wid = (blockIdx.x * blockDim.x + threadIdx.x) >> 6;
    int lane = threadIdx.x & 63;
    if (wid >= N) return;
    int s = rp[wid], e = rp[wid + 1];
    int g = lane >> 4, l16 = lane & 15;
    int cnt = e - s;
    int n_my = (cnt - g + 3) >> 2;
    int i = s + g;
    float a0 = 0, a1 = 0, a2 = 0, a3 = 0, a4 = 0, a5 = 0, a6 = 0, a7 = 0;
    size_t lo = (size_t)l16 * 8;
    while (n_my >= 4) {
        int c0 = ci[i], c1 = ci[i + 4], c2 = ci[i + 8], c3 = ci[i + 12];
        uint2 u0 = *reinterpret_cast<const uint2*>(hq + (size_t)c0 * 128 + lo);
        uint2 u1 = *reinterpret_cast<const uint2*>(hq + (size_t)c1 * 128 + lo);
        uint2 u2 = *reinterpret_cast<const uint2*>(hq + (size_t)c2 * 128 + lo);
        uint2 u3 = *reinterpret_cast<const uint2*>(hq + (size_t)c3 * 128 + lo);
        DEC8(u0); DEC8(u1); DEC8(u2); DEC8(u3);
        i += 16; n_my -= 4;
    }
    while (n_my > 0) {
        int c = ci[i];
        uint2 u = *reinterpret_cast<const uint2*>(hq + (size_t)c * 128 + lo);
        DEC8(u);
        i += 4; n_my--;
    }
#pragma unroll
    for (int off = 16; off <= 32; off <<= 1) {
        a0 += __shfl_xor(a0, off, 64); a1 += __shfl_xor(a1, off, 64);
        a2 += __shfl_xor(a2, off, 64); a3 += __shfl_xor(a3, off, 64);
        a4 += __shfl_xor(a4, off, 64); a5 += __shfl_xor(a5, off, 64);
        a6 += __shfl_xor(a6, off, 64); a7 += __shfl_xor(a7, off, 64);
    }
    if (lane < 16) {
        float id = inv_deg[wid];
        uint4 o;
        o.x = bpack(a0 * id, a1 * id); o.y = bpack(a2 * id, a3 * id);
        o.z = bpack(a4 * id, a5 * id); o.w = bpack(a6 * id, a7 * id);
        *reinterpret_cast<uint4*>(out + (size_t)wid * ldo + l16 * 8) = o;
    }
}

__global__ void k_agg47fq(const unsigned char* __restrict__ p3q, const int* __restrict__ rp,
                          const int* __restrict__ ci, const float* __restrict__ inv_deg,
                          const float* __restrict__ q3, float* __restrict__ out,
                          int N, int OUTD) {
    int wid = (blockIdx.x * blockDim.x + threadIdx.x) >> 6;
    int lane = threadIdx.x & 63;
    if (wid >= N) return;
    int s = rp[wid], e = rp[wid + 1];
    int g = lane >> 4, l16 = lane & 15;
    int cnt = e - s;
    int n_my = (cnt - g + 3) >> 2;
    int i = s + g;
    float a0 = 0, a1 = 0, a2 = 0, a3 = 0;
    size_t lo = (size_t)l16 * 4;
    while (n_my >= 4) {
        int c0 = ci[i], c1 = ci[i + 4], c2 = ci[i + 8], c3 = ci[i + 12];
        unsigned u0 = *reinterpret_cast<const unsigned*>(p3q + (size_t)c0 * 64 + lo);
        unsigned u1 = *reinterpret_cast<const unsigned*>(p3q + (size_t)c1 * 64 + lo);
        unsigned u2 = *reinterpret_cast<const unsigned*>(p3q + (size_t)c2 * 64 + lo);
        unsigned u3 = *reinterpret_cast<const unsigned*>(p3q + (size_t)c3 * 64 + lo);
        DEC4(u0); DEC4(u1); DEC4(u2); DEC4(u3);
        i += 16; n_my -= 4;
    }
    while (n_my > 0) {
        int c = ci[i];
        unsigned u = *reinterpret_cast<const unsigned*>(p3q + (size_t)c * 64 + lo);
        DEC4(u);
        i += 4; n_my--;
    }
#pragma unroll
    for (int off = 16; off <= 32; off <<= 1) {
        a0 += __shfl_xor(a0, off, 64); a1 += __shfl_xor(a1, off, 64);
        a2 += __shfl_xor(a2, off, 64); a3 += __shfl_xor(a3, off, 64);
    }
    float id = inv_deg[wid];
    int c0 = l16 * 4;
    float z0 = (c0 + 0 < OUTD) ? a0 * id + q3[(size_t)wid * 48 + c0 + 0] : -INFINITY;
    float z1 = (c0 + 1 < OUTD) ? a1 * id + q3[(size_t)wid * 48 + c0 + 1] : -INFINITY;
    float z2 = (c0 + 2 < OUTD) ? a2 * id + q3[(size_t)wid * 48 + c0 + 2] : -INFINITY;
    float z3 = (c0 + 3 < OUTD) ? a3 * id + q3[(size_t)wid * 48 + c0 + 3] : -INFINITY;
    float m = fmaxf(fmaxf(z0, z1), fmaxf(z2, z3));
#pragma unroll
    for (int off = 1; off <= 8; off <<= 1) m = fmaxf(m, __shfl_xor(m, off, 64));
    float es = ((c0 + 0 < OUTD) ? __expf(z0 - m) : 0.f) + ((c0 + 1 < OUTD) ? __expf(z1 - m) : 0.f)
             + ((c0 + 2 < OUTD) ? __expf(z2 - m) : 0.f) + ((c0 + 3 < OUTD) ? __expf(z3 - m) : 0.f);
#pragma unroll
    for (int off = 1; off <= 8; off <<= 1) es += __shfl_xor(es, off, 64);
    float ls = __logf(es) + m;
    if (lane < 16) {
        if (c0 + 0 < OUTD) out[(size_t)wid * OUTD + c0 + 0] = z0 - ls;
        if (c0 + 1 < OUTD) out[(size_t)wid * OUTD + c0 + 1] = z1 - ls;
        if (c0 + 2 < OUTD) out[(size_t)wid * OUTD + c0 + 2] = z2 - ls;
        if (c0 + 3 < OUTD) out[(size_t)wid * OUTD + c0 + 3] = z3 - ls;
    }
}

// ---------------- bf16 MFMA GEMM, 128x128 tile (m97 shape), R1 pipeline ----
// Per-k-step amortization fix: 16 MFMA + 16KB staged per step (vs 8+12KB of
// the 64-row tile) -- halves the fixed per-step cost (2 barriers + wait +
// ds_reads) per FLOP, and halves per-block A traffic. Structure = R1's
// best-measured: 2-deep LDS dbuf, issue stage(t+1) then s_waitcnt vmcnt(4),
// two barriers per k-step. 4 waves of 64x64 (acc[4][4], 64 VGPR).
// EPI=2: bf16 z + per-block psum[bx*256+col]. EPI=1: p3q fp8 + q3 f32.

template <int EPI>
__global__ __launch_bounds__(256) void k_mgemm(
    const ushort* __restrict__ A, const ushort* __restrict__ Wt,
    const float* __restrict__ bias, ushort* __restrict__ outb,
    unsigned char* __restrict__ outq,
    float* __restrict__ q3, float* __restrict__ psum, float* __restrict__ psq,
    int Nrows, int K, int M) {
    __shared__ __align__(16) ushort sA[2][128 * 32];
    __shared__ __align__(16) ushort sB[2][128 * 32];
    __shared__ float red[2][2][4][16][2];
    const int tid = threadIdx.x;
    const int w = tid >> 6, l = tid & 63;
    const int wr = w >> 1, wc = w & 1;
    const int row0 = blockIdx.x * 128, col0 = blockIdx.y * 128;
    const int li = l & 15, kg = l >> 4;

    // staging addresses (k-invariant). 512 16B-chunks each for A and B:
    // chunk c: row r=c>>2, k-group kgl=((c&3)-(r>>1))&3 (XOR-ish swizzle,
    // matched on the ds_read side; measured 0 bank conflicts).
    const int rA0 = tid >> 2, kglA0 = ((tid & 3) - (rA0 >> 1)) & 3;
    int grA0 = row0 + rA0; if (grA0 >= Nrows) grA0 = Nrows - 1;
    const ushort* gpA0 = A + (size_t)grA0 * K + kglA0 * 8;
    const int cA1 = tid + 256;
    const int rA1 = cA1 >> 2, kglA1 = ((cA1 & 3) - (rA1 >> 1)) & 3;
    int grA1 = row0 + rA1; if (grA1 >= Nrows) grA1 = Nrows - 1;
    const ushort* gpA1 = A + (size_t)grA1 * K + kglA1 * 8;

    const int rB0 = tid >> 2, kglB0 = ((tid & 3) - (rB0 >> 1)) & 3;
    const ushort* gpB0 = Wt + (size_t)(col0 + rB0) * K + kglB0 * 8;
    const int cB1 = tid + 256;
    const int rB1 = cB1 >> 2, kglB1 = ((cB1 & 3) - (rB1 >> 1)) & 3;
    const ushort* gpB1 = Wt + (size_t)(col0 + rB1) * K + kglB1 * 8;

    const int nk = K >> 5;
    auto stageT = [&](int t) {
        const int kt = t << 5;
        const int buf = t & 1;
        async16(gpA0 + kt, &sA[buf][(size_t)tid * 8]);
        async16(gpA1 + kt, &sA[buf][(size_t)cA1 * 8]);
        async16(gpB0 + kt, &sB[buf][(size_t)tid * 8]);
        async16(gpB1 + kt, &sB[buf][(size_t)cB1 * 8]);
    };

    stageT(0);

    f32x4 acc[4][4] = {};

    for (int t = 0; t < nk; ++t) {
        if (t + 1 < nk) {
            stageT(t + 1);
            asm volatile("s_waitcnt vmcnt(4)" ::: "memory");  // tile t landed
        } else {
            asm volatile("s_waitcnt vmcnt(0)" ::: "memory");
        }
        __builtin_amdgcn_s_barrier();          // tile t resident for all waves
        __builtin_amdgcn_sched_barrier(0);     // don't hoist ds_reads above

        const int buf = t & 1;
        bf16x8 af[4], bfr[4];
#pragma unroll
        for (int m = 0; m < 4; m++) {
            int r = wr * 64 + m * 16 + li;
            af[m] = *reinterpret_cast<const bf16x8*>(&sA[buf][(r * 4 + ((kg + (r >> 1)) & 3)) * 8]);
        }
#pragma unroll
        for (int n = 0; n < 4; n++) {
            int r = wc * 64 + n * 16 + li;
            bfr[n] = *reinterpret_cast<const bf16x8*>(&sB[buf][(r * 4 + ((kg + (r >> 1)) & 3)) * 8]);
        }
#pragma unroll
        for (int m = 0; m < 4; m++)
#pragma unroll
            for (int n = 0; n < 4; n++)
                acc[m][n] = __builtin_amdgcn_mfma_f32_16x16x32_bf16(af[m], bfr[n], acc[m][n], 0, 0, 0);
        __builtin_amdgcn_sched_barrier(0);
        __builtin_amdgcn_s_barrier();          // all waves done reading tile t
    }

    if constexpr (EPI == 2) {
#pragma unroll
        for (int n = 0; n < 4; n++) {
            int col = col0 + wc * 64 + n * 16 + li;
            float b = bias[col];
            float s = 0.f, sq = 0.f;
#pragma unroll
            for (int m = 0; m < 4; m++) {
                int rbase = row0 + wr * 64 + m * 16 + kg * 4;
#pragma unroll
                for (int qi = 0; qi < 4; qi++) {
                    int row = rbase + qi;
                    if (row < Nrows) {
                        float v = acc[m][n][qi] + b;
                        outb[(size_t)row * M + col] = f32_to_bf16(v);
                        s += v; sq += v * v;
                    }
                }
            }
            s += __shfl_xor(s, 16, 64); s += __shfl_xor(s, 32, 64);
            sq += __shfl_xor(sq, 16, 64); sq += __shfl_xor(sq, 32, 64);
            if (kg == 0) { red[wr][wc][n][li][0] = s; red[wr][wc][n][li][1] = sq; }
        }
        __syncthreads();
        if (wr == 0 && kg == 0) {
#pragma unroll
            for (int n = 0; n < 4; n++) {
                int gcol = col0 + wc * 64 + n * 16 + li;
                psum[(size_t)blockIdx.x * 256 + gcol] = red[0][wc][n][li][0] + red[1][wc][n][li][0];
                psq[(size_t)blockIdx.x * 256 + gcol] = red[0][wc][n][li][1] + red[1][wc][n][li][1];
            }
        }
    } else {
#pragma unroll
        for (int n = 0; n < 4; n++) {
            int col = wc * 64 + n * 16 + li;
#pragma unroll
            for (int m = 0; m < 4; m++) {
                int rbase = row0 + wr * 64 + m * 16 + kg * 4;
#pragma unroll
                for (int qi = 0; qi < 4; qi++) {
                    int row = rbase + qi;
                    if (row >= Nrows) continue;
                    float v = acc[m][n][qi];
                    if (wc == 0) {
                        outq[(size_t)row * 64 + col] = f32_to_fp8(col < 47 ? v : 0.f);
                    } else {
                        int qc = col - 64;
                        if (qc < 47) q3[(size_t)row * 48 + qc] = v + bias[qc];
                    }
                }
            }
        }
    }
}

// ---------------- BN finalize + apply ----------------

__global__ void k_bn_final(const float* __restrict__ psum, const float* __restrict__ psq,
                           int nb, int N, const float* __restrict__ g,
                           const float* __restrict__ be, float* __restrict__ scale,
                           float* __restrict__ shift) {
    int c = blockIdx.x;
    int t = threadIdx.x;
    float s = 0.f, q = 0.f;
    for (int b = t; b < nb; b += 256) { s += psum[(size_t)b * 256 + c]; q += psq[(size_t)b * 256 + c]; }
#pragma unroll
    for (int off = 32; off; off >>= 1) { s += __shfl_xor(s, off, 64); q += __shfl_xor(q, off, 64); }
    __shared__ float ls[4], lq[4];
    int wv = t >> 6;
    if ((t & 63) == 0) { ls[wv] = s; lq[wv] = q; }
    __syncthreads();
    if (t == 0) {
        s = ls[0] + ls[1] + ls[2] + ls[3];
        q = lq[0] + lq[1] + lq[2] + lq[3];
        float mu = s / (float)N;
        float var = q / (float)N - mu * mu;
        float sc = g[c] * rsqrtf(var + EPS);
        scale[c] = sc;
        shift[c] = be[c] - mu * sc;
    }
}

__global__ void k_bn_apply_b(const ushort* __restrict__ zb, long total8,
                             const float* __restrict__ scale, const float* __restrict__ shift,
                             ushort* __restrict__ outb, int ldo, int off,
                             unsigned char* __restrict__ hq) {
    long i = blockIdx.x * (long)blockDim.x + threadIdx.x;
    long stride = (long)gridDim.x * blockDim.x;
    for (; i < total8; i += stride) {
        long idx = i * 8;
        int row = (int)(idx >> 8);
        int c = (int)(idx & 255);
        uint4 u = *reinterpret_cast<const uint4*>(zb + idx);
        float y0 = fmaxf(blo(u.x) * scale[c + 0] + shift[c + 0], 0.f);
        float y1 = fmaxf(bhi(u.x) * scale[c + 1] + shift[c + 1], 0.f);
        float y2 = fmaxf(blo(u.y) * scale[c + 2] + shift[c + 2], 0.f);
        float y3 = fmaxf(bhi(u.y) * scale[c + 3] + shift[c + 3], 0.f);
        float y4 = fmaxf(blo(u.z) * scale[c + 4] + shift[c + 4], 0.f);
        float y5 = fmaxf(bhi(u.z) * scale[c + 5] + shift[c + 5], 0.f);
        float y6 = fmaxf(blo(u.w) * scale[c + 6] + shift[c + 6], 0.f);
        float y7 = fmaxf(bhi(u.w) * scale[c + 7] + shift[c + 7], 0.f);
        uint4 o;
        o.x = bpack(y0, y1); o.y = bpack(y2, y3); o.z = bpack(y4, y5); o.w = bpack(y6, y7);
        *reinterpret_cast<uint4*>(outb + (size_t)row * ldo + off + c) = o;
        if (hq) {
            unsigned lo8 = 0, hi8 = 0;
            lo8 = (unsigned)__builtin_amdgcn_cvt_pk_fp8_f32(y0, y1, 0, false);
            lo8 = (unsigned)__builtin_amdgcn_cvt_pk_fp8_f32(y2, y3, (int)lo8, true);
            hi8 = (unsigned)__builtin_amdgcn_cvt_pk_fp8_f32(y4, y5, 0, false);
            hi8 = (unsigned)__builtin_amdgcn_cvt_pk_fp8_f32(y6, y7, (int)hi8, true);
            *reinterpret_cast<uint2*>(hq + (size_t)row * 256 + c) = make_uint2(lo8, hi8);
        }
    }
}

// ---------------- host ----------------

extern "C" void kernel_launch(void* const* d_in, const int* in_sizes, int n_in,
                              void* d_out, int out_size, void* d_ws, size_t ws_size,
                              hipStream_t stream) {
    const float* x   = (const float*)d_in[0];
    const int*   ei  = (const int*)d_in[1];
    const float* w1l = (const float*)d_in[2];
    const float* w1r = (const float*)d_in[3];
    const float* b1  = (const float*)d_in[4];
    const float* g1  = (const float*)d_in[5];
    const float* be1 = (const float*)d_in[6];
    const float* w2l = (const float*)d_in[7];
    const float* w2r = (const float*)d_in[8];
    const float* b2  = (const float*)d_in[9];
    const float* g2  = (const float*)d_in[10];
    const float* be2 = (const float*)d_in[11];
    const float* w3l = (const float*)d_in[12];
    const float* w3r = (const float*)d_in[13];
    const float* b3  = (const float*)d_in[14];
    float* out = (float*)d_out;

    const int INDIM = 128, HID = 256;
    int N = in_sizes[0] / INDIM;
    int E = in_sizes[1] / 2;
    int OUTD = in_sizes[14];
    const int* src = ei;
    const int* dst = ei + E;
    int NB = (N + 255) >> 8;

    size_t off = 0;
    auto carve = [&](size_t bytes) -> char* {
        char* p = (char*)d_ws + off;
        off = (off + bytes + 255) & ~(size_t)255;
        return p;
    };
    int*    row_ptr  = (int*)carve((size_t)(N + 1) * 4);
    float*  inv_deg  = (float*)carve((size_t)N * 4);
    int*    gcnt     = (int*)carve(256 * 4);
    int*    gbase    = (int*)carve(256 * 4);
    int*    gtail    = (int*)carve(256 * 4);
    uint2*  pairs    = (uint2*)carve((size_t)E * 8);
    int*    colidx   = (int*)carve((size_t)E * 4);
    float*  psum     = (float*)carve((size_t)256 * 1024 * 4);
    float*  psq      = (float*)carve((size_t)256 * 1024 * 4);
    float*  bnscale  = (float*)carve(256 * 4);
    float*  bnshift  = (float*)carve(256 * 4);
    ushort* Wt1      = (ushort*)carve((size_t)256 * 256 * 2);
    ushort* Wt2      = (ushort*)carve((size_t)256 * 512 * 2);
    ushort* Wt3      = (ushort*)carve((size_t)128 * 256 * 2);
    ushort* cat1     = (ushort*)carve((size_t)N * 256 * 2);   // [agg(x)|xb] bf16
    unsigned char* xq  = (unsigned char*)carve((size_t)N * 128);  // x fp8
    unsigned char* h1q = (unsigned char*)carve((size_t)N * 256);  // h1 fp8
    ushort* cat2     = (ushort*)carve((size_t)N * 512 * 2);   // [agg(h1)|h1]; later h2b
    ushort* zb       = (ushort*)carve((size_t)N * HID * 2);   // bf16 z1/z2
    unsigned char* p3q = (unsigned char*)carve((size_t)N * 64);   // p3 fp8
    float*  q3       = (float*)carve((size_t)N * 48 * 4);
    (void)ws_size; (void)n_in; (void)out_size;

    hipMemsetAsync(gcnt, 0, 256 * 4, stream);
    hipMemsetAsync(Wt3, 0, (size_t)128 * 256 * 2, stream);

    int bktB = (E + 8191) / 8192;
    int cvtB = (N * 128 + 255) / 256;
    k_pre<<<bktB + cvtB + 256, 256, 0, stream>>>(dst, E, gcnt, x, cat1, xq, N * 128,
                                                 w1l, w1r, w2l, w2r, w3l, w3r,
                                                 Wt1, Wt2, Wt3, bktB, cvtB);
    k_bscan<<<1, 256, 0, stream>>>(gcnt, gbase, gtail, NB);
    k_scatter<<<bktB, 256, 0, stream>>>(src, dst, E, gtail, pairs, NB);
    k_brow<<<NB, 256, 0, stream>>>(pairs, gbase, gcnt, row_ptr, inv_deg, N, E);
    k_bfill<<<NB, 256, 0, stream>>>(pairs, gbase, gcnt, row_ptr, colidx, N);

    int aggBlocks = (N + 3) / 4;
    int MB = (N + 127) >> 7;   // 128-row tiles (391)
    long total8 = (long)N * 32;
    ushort* h2b = cat2;  // reuse

    // ---- layer 1 ----
    k_agg128q<<<aggBlocks, 256, 0, stream>>>(xq, row_ptr, colidx, inv_deg, cat1, 256, N);
    k_mgemm<2><<<dim3(MB, 2), 256, 0, stream>>>(cat1, Wt1, b1, zb, nullptr, nullptr,
                                                psum, psq, N, 256, 256);
    k_bn_final<<<256, 256, 0, stream>>>(psum, psq, MB, N, g1, be1, bnscale, bnshift);
    k_bn_apply_b<<<1024, 256, 0, stream>>>(zb, total8, bnscale, bnshift, cat2, 512, 256, h1q);

    // ---- layer 2 ----
    k_agg256q<<<aggBlocks, 256, 0, stream>>>(h1q, row_ptr, colidx, inv_deg, cat2, 512, N);
    k_mgemm<2><<<dim3(MB, 2), 256, 0, stream>>>(cat2, Wt2, b2, zb, nullptr, nullptr,
                                                psum, psq, N, 512, 256);
    k_bn_final<<<256, 256, 0, stream>>>(psum, psq, MB, N, g2, be2, bnscale, bnshift);
    k_bn_apply_b<<<1024, 256, 0, stream>>>(zb, total8, bnscale, bnshift, h2b, 256, 0, nullptr);

    // ---- layer 3: fp8 p3 / f32 q3 epilogue, then fused agg + log_softmax ----
    k_mgemm<1><<<dim3(MB, 1), 256, 0, stream>>>(h2b, Wt3, b3, nullptr, p3q, q3,
                                                nullptr, nullptr, N, 256, 128);
    k_agg47fq<<<aggBlocks, 256, 0, stream>>>(p3q, row_ptr, colidx, inv_deg, q3, out, N, OUTD);
}

// Round 6
// 267.200 us; speedup vs baseline: 1.1237x; 1.1083x over previous
//
#include <hip/hip_runtime.h>
#include <hip/hip_bf16.h>
#include <cmath>

#define EPS 1e-5f

typedef __attribute__((ext_vector_type(8))) short bf16x8;
typedef __attribute__((ext_vector_type(4))) float f32x4;
typedef __attribute__((ext_vector_type(2))) float floatx2;

static __device__ __forceinline__ ushort f32_to_bf16(float f) {
    __hip_bfloat16 h = __float2bfloat16(f);
    return __builtin_bit_cast(ushort, h);
}
static __device__ __forceinline__ float blo(unsigned u) { return __uint_as_float(u << 16); }
static __device__ __forceinline__ float bhi(unsigned u) { return __uint_as_float(u & 0xffff0000u); }
static __device__ __forceinline__ unsigned bpack(float a, float b) {
    return (unsigned)f32_to_bf16(a) | ((unsigned)f32_to_bf16(b) << 16);
}
static __device__ __forceinline__ unsigned char f32_to_fp8(float v) {
    return (unsigned char)(__builtin_amdgcn_cvt_pk_fp8_f32(v, 0.f, 0, false) & 0xff);
}

static __device__ __forceinline__ void async16(const void* g, void* l) {
    __builtin_amdgcn_global_load_lds(
        (const __attribute__((address_space(1))) unsigned int*)g,
        (__attribute__((address_space(3))) unsigned int*)l, 16, 0, 0);
}

// bijective XCD chunk swizzle (m204): hardware assigns block b to XCD b%8;
// remap so each XCD processes a CONTIGUOUS range of logical workgroups.
static __device__ __forceinline__ int xcd_swz(int bid, int nwg) {
    int q = nwg >> 3, r = nwg & 7;
    int xcd = bid & 7, loc = bid >> 3;
    return (xcd < r ? xcd * (q + 1) : r * (q + 1) + (xcd - r) * q) + loc;
}

// decode 8 fp8 (uint2) -> accumulate into a0..a7
#define DEC8(u) { floatx2 p_; \
    p_ = __builtin_amdgcn_cvt_pk_f32_fp8((int)(u).x, false); a0 += p_.x; a1 += p_.y; \
    p_ = __builtin_amdgcn_cvt_pk_f32_fp8((int)(u).x, true);  a2 += p_.x; a3 += p_.y; \
    p_ = __builtin_amdgcn_cvt_pk_f32_fp8((int)(u).y, false); a4 += p_.x; a5 += p_.y; \
    p_ = __builtin_amdgcn_cvt_pk_f32_fp8((int)(u).y, true);  a6 += p_.x; a7 += p_.y; }
#define DEC4(u) { floatx2 p_; \
    p_ = __builtin_amdgcn_cvt_pk_f32_fp8((int)(u), false); a0 += p_.x; a1 += p_.y; \
    p_ = __builtin_amdgcn_cvt_pk_f32_fp8((int)(u), true);  a2 += p_.x; a3 += p_.y; }

// ---------------- prologue: bucket-count + x->bf16+fp8 + weight prep ----------------

__global__ void k_pre(const int* __restrict__ dst, int E, int* __restrict__ gcnt,
                      const float* __restrict__ x, ushort* __restrict__ cat1,
                      unsigned char* __restrict__ xq, int NX,
                      const float* __restrict__ w1l, const float* __restrict__ w1r,
                      const float* __restrict__ w2l, const float* __restrict__ w2r,
                      const float* __restrict__ w3l, const float* __restrict__ w3r,
                      ushort* __restrict__ Wt1, ushort* __restrict__ Wt2,
                      ushort* __restrict__ Wt3, int bktB, int cvtB) {
    int b = blockIdx.x;
    int t = threadIdx.x;
    if (b < bktB) {
        __shared__ int hist[256];
        hist[t] = 0;
        __syncthreads();
        int base = b * 8192;
        int end = base + 8192; if (end > E) end = E;
        for (int i = base + t; i < end; i += 256)
            atomicAdd(&hist[((unsigned)dst[i]) >> 8], 1);
        __syncthreads();
        if (hist[t]) atomicAdd(&gcnt[t], hist[t]);
    } else if (b < bktB + cvtB) {
        int i = (b - bktB) * 256 + t;
        if (i < NX) {
            int row = i >> 7, c = i & 127;
            float v = x[i];
            cat1[(size_t)row * 256 + 128 + c] = f32_to_bf16(v);
            xq[(size_t)row * 128 + c] = f32_to_fp8(v);
        }
    } else {
        int tt = (b - bktB - cvtB) * 256 + t;
        if (tt < 128 * 256) {
            int k = tt >> 8, c = tt & 255;
            Wt1[(size_t)c * 256 + k] = f32_to_bf16(w1l[tt]);
            Wt1[(size_t)c * 256 + 128 + k] = f32_to_bf16(w1r[tt]);
        }
        if (tt < 256 * 256) {
            int k = tt >> 8, c = tt & 255;
            Wt2[(size_t)c * 512 + k] = f32_to_bf16(w2l[tt]);
            Wt2[(size_t)c * 512 + 256 + k] = f32_to_bf16(w2r[tt]);
        }
        if (tt < 256 * 47) {
            int k = tt / 47, c = tt - k * 47;
            Wt3[(size_t)c * 256 + k] = f32_to_bf16(w3l[tt]);
            Wt3[(size_t)(64 + c) * 256 + k] = f32_to_bf16(w3r[tt]);
        }
    }
}

__global__ void k_bscan(const int* __restrict__ gcnt, int* __restrict__ gbase,
                        int* __restrict__ gtail, int NB) {
    __shared__ int s[256];
    int t = threadIdx.x;
    int v = (t < NB) ? gcnt[t] : 0;
    s[t] = v;
    __syncthreads();
    for (int off = 1; off < 256; off <<= 1) {
        int add = (t >= off) ? s[t - off] : 0;
        __syncthreads();
        s[t] += add;
        __syncthreads();
    }
    int excl = s[t] - v;
    if (t < NB) { gbase[t] = excl; gtail[t] = excl; }
}

__global__ void k_scatter(const int* __restrict__ src, const int* __restrict__ dst,
                          int E, int* __restrict__ gtail, uint2* __restrict__ pairs,
                          int NB) {
    __shared__ int hist[256];
    __shared__ int lcur[256];
    int t = threadIdx.x;
    hist[t] = 0;
    __syncthreads();
    int base = blockIdx.x * 8192;
    int end = base + 8192; if (end > E) end = E;
    for (int i = base + t; i < end; i += 256)
        atomicAdd(&hist[((unsigned)dst[i]) >> 8], 1);
    __syncthreads();
    if (t < NB && hist[t]) lcur[t] = atomicAdd(&gtail[t], hist[t]);
    __syncthreads();
    for (int i = base + t; i < end; i += 256) {
        int dd = dst[i];
        int pos = atomicAdd(&lcur[((unsigned)dd) >> 8], 1);
        pairs[pos] = make_uint2((unsigned)src[i], (unsigned)dd);
    }
}

__global__ void k_brow(const uint2* __restrict__ pairs, const int* __restrict__ gbase,
                       const int* __restrict__ gcnt, int* __restrict__ row_ptr,
                       float* __restrict__ inv_deg, int N, int E) {
    int b = blockIdx.x;
    __shared__ int hist[256];
    __shared__ int sc[256];
    int t = threadIdx.x;
    hist[t] = 0;
    __syncthreads();
    int s = gbase[b], cnt = gcnt[b];
    for (int i = t; i < cnt; i += 256) {
        uint2 p = pairs[s + i];
        atomicAdd(&hist[p.y & 255], 1);
    }
    __syncthreads();
    int d = hist[t];
    sc[t] = d;
    __syncthreads();
    for (int off = 1; off < 256; off <<= 1) {
        int add = (t >= off) ? sc[t - off] : 0;
        __syncthreads();
        sc[t] += add;
        __syncthreads();
    }
    int node = b * 256 + t;
    if (node < N) {
        row_ptr[node] = s + sc[t] - d;
        inv_deg[node] = 1.0f / (float)(d > 1 ? d : 1);
    }
    if (b == 0 && t == 0) row_ptr[N] = E;
}

__global__ void k_bfill(const uint2* __restrict__ pairs, const int* __restrict__ gbase,
                        const int* __restrict__ gcnt, const int* __restrict__ row_ptr,
                        int* __restrict__ colidx, int N) {
    int b = blockIdx.x;
    __shared__ int cur[256];
    int t = threadIdx.x;
    int node = b * 256 + t;
    cur[t] = (node < N) ? row_ptr[node] : 0;
    __syncthreads();
    int s = gbase[b], cnt = gcnt[b];
    for (int i = t; i < cnt; i += 256) {
        uint2 p = pairs[s + i];
        int pos = atomicAdd(&cur[p.y & 255], 1);
        colidx[pos] = (int)p.x;
    }
}

// ---------------- fp8 aggregation: wave per node, 4-deep ILP ----------------

__global__ void k_agg256q(const unsigned char* __restrict__ hq, const int* __restrict__ rp,
                          const int* __restrict__ ci, const float* __restrict__ inv_deg,
                          ushort* __restrict__ out, int ldo, int N) {
    int wid = (blockIdx.x * blockDim.x + threadIdx.x) >> 6;
    int lane = threadIdx.x & 63;
    if (wid >= N) return;
    int s = rp[wid], e = rp[wid + 1];
    int half = lane >> 5, l32 = lane & 31;
    int cnt = e - s;
    int n_my = (cnt - half + 1) >> 1;
    int i = s + half;
    float a0 = 0, a1 = 0, a2 = 0, a3 = 0, a4 = 0, a5 = 0, a6 = 0, a7 = 0;
    size_t lo = (size_t)l32 * 8;
    while (n_my >= 4) {
        int c0 = ci[i], c1 = ci[i + 2], c2 = ci[i + 4], c3 = ci[i + 6];
        uint2 u0 = *reinterpret_cast<const uint2*>(hq + (size_t)c0 * 256 + lo);
        uint2 u1 = *reinterpret_cast<const uint2*>(hq + (size_t)c1 * 256 + lo);
        uint2 u2 = *reinterpret_cast<const uint2*>(hq + (size_t)c2 * 256 + lo);
        uint2 u3 = *reinterpret_cast<const uint2*>(hq + (size_t)c3 * 256 + lo);
        DEC8(u0); DEC8(u1); DEC8(u2); DEC8(u3);
        i += 8; n_my -= 4;
    }
    while (n_my > 0) {
        int c = ci[i];
        uint2 u = *reinterpret_cast<const uint2*>(hq + (size_t)c * 256 + lo);
        DEC8(u);
        i += 2; n_my--;
    }
    a0 += __shfl_xor(a0, 32, 64); a1 += __shfl_xor(a1, 32, 64);
    a2 += __shfl_xor(a2, 32, 64); a3 += __shfl_xor(a3, 32, 64);
    a4 += __shfl_xor(a4, 32, 64); a5 += __shfl_xor(a5, 32, 64);
    a6 += __shfl_xor(a6, 32, 64); a7 += __shfl_xor(a7, 32, 64);
    if (half == 0) {
        float id = inv_deg[wid];
        uint4 o;
        o.x = bpack(a0 * id, a1 * id); o.y = bpack(a2 * id, a3 * id);
        o.z = bpack(a4 * id, a5 * id); o.w = bpack(a6 * id, a7 * id);
        *reinterpret_cast<uint4*>(out + (size_t)wid * ldo + l32 * 8) = o;
    }
}

__global__ void k_agg128q(const unsigned char* __restrict__ hq, const int* __restrict__ rp,
                          const int* __restrict__ ci, const float* __restrict__ inv_deg,
                          ushort* __restrict__ out, int ldo, int N) {
    int wid = (blockIdx.x * blockDim.x + threadIdx.x) >> 6;
    int lane = threadIdx.x & 63;
    if (wid >= N) return;
    int s = rp[wid], e = rp[wid + 1];
    int g = lane >> 4, l16 = lane & 15;
    int cnt = e - s;
    int n_my = (cnt - g + 3) >> 2;
    int i = s + g;
    float a0 = 0, a1 = 0, a2 = 0, a3 = 0, a4 = 0, a5 = 0, a6 = 0, a7 = 0;
    size_t lo = (size_t)l16 * 8;
    while (n_my >= 4) {
        int c0 = ci[i], c1 = ci[i + 4], c2 = ci[i + 8], c3 = ci[i + 12];
        uint2 u0 = *reinterpret_cast<const uint2*>(hq + (size_t)c0 * 128 + lo);
        uint2 u1 = *reinterpret_cast<const uint2*>(hq + (size_t)c1 * 128 + lo);
        uint2 u2 = *reinterpret_cast<const uint2*>(hq + (size_t)c2 * 128 + lo);
        uint2 u3 = *reinterpret_cast<const uint2*>(hq + (size_t)c3 * 128 + lo);
        DEC8(u0); DEC8(u1); DEC8(u2); DEC8(u3);
        i += 16; n_my -= 4;
    }
    while (n_my > 0) {
        int c = ci[i];
        uint2 u = *reinterpret_cast<const uint2*>(hq + (size_t)c * 128 + lo);
        DEC8(u);
        i += 4; n_my--;
    }
#pragma unroll
    for (int off = 16; off <= 32; off <<= 1) {
        a0 += __shfl_xor(a0, off, 64); a1 += __shfl_xor(a1, off, 64);
        a2 += __shfl_xor(a2, off, 64); a3 += __shfl_xor(a3, off, 64);
        a4 += __shfl_xor(a4, off, 64); a5 += __shfl_xor(a5, off, 64);
        a6 += __shfl_xor(a6, off, 64); a7 += __shfl_xor(a7, off, 64);
    }
    if (lane < 16) {
        float id = inv_deg[wid];
        uint4 o;
        o.x = bpack(a0 * id, a1 * id); o.y = bpack(a2 * id, a3 * id);
        o.z = bpack(a4 * id, a5 * id); o.w = bpack(a6 * id, a7 * id);
        *reinterpret_cast<uint4*>(out + (size_t)wid * ldo + l16 * 8) = o;
    }
}

__global__ void k_agg47fq(const unsigned char* __restrict__ p3q, const int* __restrict__ rp,
                          const int* __restrict__ ci, const float* __restrict__ inv_deg,
                          const float* __restrict__ q3, float* __restrict__ out,
                          int N, int OUTD) {
    int wid = (blockIdx.x * blockDim.x + threadIdx.x) >> 6;
    int lane = threadIdx.x & 63;
    if (wid >= N) return;
    int s = rp[wid], e = rp[wid + 1];
    int g = lane >> 4, l16 = lane & 15;
    int cnt = e - s;
    int n_my = (cnt - g + 3) >> 2;
    int i = s + g;
    float a0 = 0, a1 = 0, a2 = 0, a3 = 0;
    size_t lo = (size_t)l16 * 4;
    while (n_my >= 4) {
        int c0 = ci[i], c1 = ci[i + 4], c2 = ci[i + 8], c3 = ci[i + 12];
        unsigned u0 = *reinterpret_cast<const unsigned*>(p3q + (size_t)c0 * 64 + lo);
        unsigned u1 = *reinterpret_cast<const unsigned*>(p3q + (size_t)c1 * 64 + lo);
        unsigned u2 = *reinterpret_cast<const unsigned*>(p3q + (size_t)c2 * 64 + lo);
        unsigned u3 = *reinterpret_cast<const unsigned*>(p3q + (size_t)c3 * 64 + lo);
        DEC4(u0); DEC4(u1); DEC4(u2); DEC4(u3);
        i += 16; n_my -= 4;
    }
    while (n_my > 0) {
        int c = ci[i];
        unsigned u = *reinterpret_cast<const unsigned*>(p3q + (size_t)c * 64 + lo);
        DEC4(u);
        i += 4; n_my--;
    }
#pragma unroll
    for (int off = 16; off <= 32; off <<= 1) {
        a0 += __shfl_xor(a0, off, 64); a1 += __shfl_xor(a1, off, 64);
        a2 += __shfl_xor(a2, off, 64); a3 += __shfl_xor(a3, off, 64);
    }
    float id = inv_deg[wid];
    int c0 = l16 * 4;
    float z0 = (c0 + 0 < OUTD) ? a0 * id + q3[(size_t)wid * 48 + c0 + 0] : -INFINITY;
    float z1 = (c0 + 1 < OUTD) ? a1 * id + q3[(size_t)wid * 48 + c0 + 1] : -INFINITY;
    float z2 = (c0 + 2 < OUTD) ? a2 * id + q3[(size_t)wid * 48 + c0 + 2] : -INFINITY;
    float z3 = (c0 + 3 < OUTD) ? a3 * id + q3[(size_t)wid * 48 + c0 + 3] : -INFINITY;
    float m = fmaxf(fmaxf(z0, z1), fmaxf(z2, z3));
#pragma unroll
    for (int off = 1; off <= 8; off <<= 1) m = fmaxf(m, __shfl_xor(m, off, 64));
    float es = ((c0 + 0 < OUTD) ? __expf(z0 - m) : 0.f) + ((c0 + 1 < OUTD) ? __expf(z1 - m) : 0.f)
             + ((c0 + 2 < OUTD) ? __expf(z2 - m) : 0.f) + ((c0 + 3 < OUTD) ? __expf(z3 - m) : 0.f);
#pragma unroll
    for (int off = 1; off <= 8; off <<= 1) es += __shfl_xor(es, off, 64);
    float ls = __logf(es) + m;
    if (lane < 16) {
        if (c0 + 0 < OUTD) out[(size_t)wid * OUTD + c0 + 0] = z0 - ls;
        if (c0 + 1 < OUTD) out[(size_t)wid * OUTD + c0 + 1] = z1 - ls;
        if (c0 + 2 < OUTD) out[(size_t)wid * OUTD + c0 + 2] = z2 - ls;
        if (c0 + 3 < OUTD) out[(size_t)wid * OUTD + c0 + 3] = z3 - ls;
    }
}

// ---------------- bf16 MFMA GEMM, 64x128 tile, 2x2 waves (R1 structure) ----
// R1 pipeline (best measured): 2-deep LDS dbuf, issue stage(t+1) then
// s_waitcnt vmcnt(3), two barriers per k-step.
// NEW (R6): flat grid + bijective XCD chunk swizzle; col-half is the LOWEST
// bit of the logical id, so the two col-blocks sharing an A row-panel are
// ADJACENT in the same XCD chunk (A re-read served by same-XCD L2, not L3).
// EPI=2: bf16 z + per-row-tile psum[rt*256+col]. EPI=1: p3q fp8 + q3 f32.

template <int EPI>
__global__ __launch_bounds__(256) void k_mgemm(
    const ushort* __restrict__ A, const ushort* __restrict__ Wt,
    const float* __restrict__ bias, ushort* __restrict__ outb,
    unsigned char* __restrict__ outq,
    float* __restrict__ q3, float* __restrict__ psum, float* __restrict__ psq,
    int Nrows, int K, int M) {
    __shared__ __align__(16) ushort sA[2][64 * 32];
    __shared__ __align__(16) ushort sB[2][128 * 32];
    __shared__ float red[2][2][4][16][2];
    const int tid = threadIdx.x;
    const int w = tid >> 6, l = tid & 63;
    const int wr = w >> 1, wc = w & 1;
    const int li = l & 15, kg = l >> 4;

    const int wgid = xcd_swz(blockIdx.x, gridDim.x);
    int rt, col0;
    if constexpr (EPI == 2) { rt = wgid >> 1; col0 = (wgid & 1) * 128; }
    else                    { rt = wgid;      col0 = 0; }
    const int row0 = rt * 64;

    // staging addresses (k-invariant)
    const int rA = tid >> 2, kgpA = tid & 3;
    const int kglA = (kgpA - (rA >> 1)) & 3;
    int grA = row0 + rA; if (grA >= Nrows) grA = Nrows - 1;
    const ushort* gpA = A + (size_t)grA * K + kglA * 8;

    const int rB0 = tid >> 2, kglB0 = ((tid & 3) - (rB0 >> 1)) & 3;
    const ushort* gpB0 = Wt + (size_t)(col0 + rB0) * K + kglB0 * 8;
    const int cB1 = tid + 256;
    const int rB1 = cB1 >> 2, kglB1 = ((cB1 & 3) - (rB1 >> 1)) & 3;
    const ushort* gpB1 = Wt + (size_t)(col0 + rB1) * K + kglB1 * 8;

    f32x4 acc[2][4] = {};

    const int nk = K >> 5;
    // prologue: stage tile 0 into buffer 0
    async16(gpA, &sA[0][(size_t)tid * 8]);
    async16(gpB0, &sB[0][(size_t)tid * 8]);
    async16(gpB1, &sB[0][(size_t)cB1 * 8]);

    for (int t = 0; t < nk; ++t) {
        const int cur = t & 1;
        if (t + 1 < nk) {
            const int kt = (t + 1) << 5;
            async16(gpA + kt, &sA[cur ^ 1][(size_t)tid * 8]);
            async16(gpB0 + kt, &sB[cur ^ 1][(size_t)tid * 8]);
            async16(gpB1 + kt, &sB[cur ^ 1][(size_t)cB1 * 8]);
            asm volatile("s_waitcnt vmcnt(3)" ::: "memory");
        } else {
            asm volatile("s_waitcnt vmcnt(0)" ::: "memory");
        }
        __builtin_amdgcn_s_barrier();          // tile t resident for all waves
        __builtin_amdgcn_sched_barrier(0);     // don't hoist ds_reads above this

        bf16x8 af[2], bfr[4];
#pragma unroll
        for (int m = 0; m < 2; m++) {
            int r = wr * 32 + m * 16 + li;
            af[m] = *reinterpret_cast<const bf16x8*>(&sA[cur][(r * 4 + ((kg + (r >> 1)) & 3)) * 8]);
        }
#pragma unroll
        for (int n = 0; n < 4; n++) {
            int r = wc * 64 + n * 16 + li;
            bfr[n] = *reinterpret_cast<const bf16x8*>(&sB[cur][(r * 4 + ((kg + (r >> 1)) & 3)) * 8]);
        }
#pragma unroll
        for (int m = 0; m < 2; m++)
#pragma unroll
            for (int n = 0; n < 4; n++)
                acc[m][n] = __builtin_amdgcn_mfma_f32_16x16x32_bf16(af[m], bfr[n], acc[m][n], 0, 0, 0);
        __builtin_amdgcn_sched_barrier(0);
        __builtin_amdgcn_s_barrier();          // all waves done reading tile t
    }

    if constexpr (EPI == 2) {
#pragma unroll
        for (int n = 0; n < 4; n++) {
            int col = col0 + wc * 64 + n * 16 + li;
            float b = bias[col];
            float s = 0.f, sq = 0.f;
#pragma unroll
            for (int m = 0; m < 2; m++) {
                int rbase = row0 + wr * 32 + m * 16 + kg * 4;
#pragma unroll
                for (int qi = 0; qi < 4; qi++) {
                    int row = rbase + qi;
                    if (row < Nrows) {
                        float v = acc[m][n][qi] + b;
                        outb[(size_t)row * M + col] = f32_to_bf16(v);
                        s += v; sq += v * v;
                    }
                }
            }
            s += __shfl_xor(s, 16, 64); s += __shfl_xor(s, 32, 64);
            sq += __shfl_xor(sq, 16, 64); sq += __shfl_xor(sq, 32, 64);
            if (kg == 0) { red[wr][wc][n][li][0] = s; red[wr][wc][n][li][1] = sq; }
        }
        __syncthreads();
        if (wr == 0 && kg == 0) {
#pragma unroll
            for (int n = 0; n < 4; n++) {
                int gcol = col0 + wc * 64 + n * 16 + li;
                psum[(size_t)rt * 256 + gcol] = red[0][wc][n][li][0] + red[1][wc][n][li][0];
                psq[(size_t)rt * 256 + gcol] = red[0][wc][n][li][1] + red[1][wc][n][li][1];
            }
        }
    } else {
#pragma unroll
        for (int n = 0; n < 4; n++) {
            int col = wc * 64 + n * 16 + li;
#pragma unroll
            for (int m = 0; m < 2; m++) {
                int rbase = row0 + wr * 32 + m * 16 + kg * 4;
#pragma unroll
                for (int qi = 0; qi < 4; qi++) {
                    int row = rbase + qi;
                    if (row >= Nrows) continue;
                    float v = acc[m][n][qi];
                    if (wc == 0) {
                        outq[(size_t)row * 64 + col] = f32_to_fp8(col < 47 ? v : 0.f);
                    } else {
                        int qc = col - 64;
                        if (qc < 47) q3[(size_t)row * 48 + qc] = v + bias[qc];
                    }
                }
            }
        }
    }
}

// ---------------- BN finalize + apply ----------------

__global__ void k_bn_final(const float* __restrict__ psum, const float* __restrict__ psq,
                           int nb, int N, const float* __restrict__ g,
                           const float* __restrict__ be, float* __restrict__ scale,
                           float* __restrict__ shift) {
    int c = blockIdx.x;
    int t = threadIdx.x;
    float s = 0.f, q = 0.f;
    for (int b = t; b < nb; b += 256) { s += psum[(size_t)b * 256 + c]; q += psq[(size_t)b * 256 + c]; }
#pragma unroll
    for (int off = 32; off; off >>= 1) { s += __shfl_xor(s, off, 64); q += __shfl_xor(q, off, 64); }
    __shared__ float ls[4], lq[4];
    int wv = t >> 6;
    if ((t & 63) == 0) { ls[wv] = s; lq[wv] = q; }
    __syncthreads();
    if (t == 0) {
        s = ls[0] + ls[1] + ls[2] + ls[3];
        q = lq[0] + lq[1] + lq[2] + lq[3];
        float mu = s / (float)N;
        float var = q / (float)N - mu * mu;
        float sc = g[c] * rsqrtf(var + EPS);
        scale[c] = sc;
        shift[c] = be[c] - mu * sc;
    }
}

__global__ void k_bn_apply_b(const ushort* __restrict__ zb, long total8,
                             const float* __restrict__ scale, const float* __restrict__ shift,
                             ushort* __restrict__ outb, int ldo, int off,
                             unsigned char* __restrict__ hq) {
    long i = blockIdx.x * (long)blockDim.x + threadIdx.x;
    long stride = (long)gridDim.x * blockDim.x;
    for (; i < total8; i += stride) {
        long idx = i * 8;
        int row = (int)(idx >> 8);
        int c = (int)(idx & 255);
        uint4 u = *reinterpret_cast<const uint4*>(zb + idx);
        f32x4 sc0 = *reinterpret_cast<const f32x4*>(&scale[c]);
        f32x4 sc1 = *reinterpret_cast<const f32x4*>(&scale[c + 4]);
        f32x4 sh0 = *reinterpret_cast<const f32x4*>(&shift[c]);
        f32x4 sh1 = *reinterpret_cast<const f32x4*>(&shift[c + 4]);
        float y0 = fmaxf(blo(u.x) * sc0[0] + sh0[0], 0.f);
        float y1 = fmaxf(bhi(u.x) * sc0[1] + sh0[1], 0.f);
        float y2 = fmaxf(blo(u.y) * sc0[2] + sh0[2], 0.f);
        float y3 = fmaxf(bhi(u.y) * sc0[3] + sh0[3], 0.f);
        float y4 = fmaxf(blo(u.z) * sc1[0] + sh1[0], 0.f);
        float y5 = fmaxf(bhi(u.z) * sc1[1] + sh1[1], 0.f);
        float y6 = fmaxf(blo(u.w) * sc1[2] + sh1[2], 0.f);
        float y7 = fmaxf(bhi(u.w) * sc1[3] + sh1[3], 0.f);
        uint4 o;
        o.x = bpack(y0, y1); o.y = bpack(y2, y3); o.z = bpack(y4, y5); o.w = bpack(y6, y7);
        *reinterpret_cast<uint4*>(outb + (size_t)row * ldo + off + c) = o;
        if (hq) {
            unsigned lo8 = 0, hi8 = 0;
            lo8 = (unsigned)__builtin_amdgcn_cvt_pk_fp8_f32(y0, y1, 0, false);
            lo8 = (unsigned)__builtin_amdgcn_cvt_pk_fp8_f32(y2, y3, (int)lo8, true);
            hi8 = (unsigned)__builtin_amdgcn_cvt_pk_fp8_f32(y4, y5, 0, false);
            hi8 = (unsigned)__builtin_amdgcn_cvt_pk_fp8_f32(y6, y7, (int)hi8, true);
            *reinterpret_cast<uint2*>(hq + (size_t)row * 256 + c) = make_uint2(lo8, hi8);
        }
    }
}

// ---------------- host ----------------

extern "C" void kernel_launch(void* const* d_in, const int* in_sizes, int n_in,
                              void* d_out, int out_size, void* d_ws, size_t ws_size,
                              hipStream_t stream) {
    const float* x   = (const float*)d_in[0];
    const int*   ei  = (const int*)d_in[1];
    const float* w1l = (const float*)d_in[2];
    const float* w1r = (const float*)d_in[3];
    const float* b1  = (const float*)d_in[4];
    const float* g1  = (const float*)d_in[5];
    const float* be1 = (const float*)d_in[6];
    const float* w2l = (const float*)d_in[7];
    const float* w2r = (const float*)d_in[8];
    const float* b2  = (const float*)d_in[9];
    const float* g2  = (const float*)d_in[10];
    const float* be2 = (const float*)d_in[11];
    const float* w3l = (const float*)d_in[12];
    const float* w3r = (const float*)d_in[13];
    const float* b3  = (const float*)d_in[14];
    float* out = (float*)d_out;

    const int INDIM = 128, HID = 256;
    int N = in_sizes[0] / INDIM;
    int E = in_sizes[1] / 2;
    int OUTD = in_sizes[14];
    const int* src = ei;
    const int* dst = ei + E;
    int NB = (N + 255) >> 8;

    size_t off = 0;
    auto carve = [&](size_t bytes) -> char* {
        char* p = (char*)d_ws + off;
        off = (off + bytes + 255) & ~(size_t)255;
        return p;
    };
    int*    row_ptr  = (int*)carve((size_t)(N + 1) * 4);
    float*  inv_deg  = (float*)carve((size_t)N * 4);
    int*    gcnt     = (int*)carve(256 * 4);
    int*    gbase    = (int*)carve(256 * 4);
    int*    gtail    = (int*)carve(256 * 4);
    uint2*  pairs    = (uint2*)carve((size_t)E * 8);
    int*    colidx   = (int*)carve((size_t)E * 4);
    float*  psum     = (float*)carve((size_t)256 * 1024 * 4);
    float*  psq      = (float*)carve((size_t)256 * 1024 * 4);
    float*  bnscale  = (float*)carve(256 * 4);
    float*  bnshift  = (float*)carve(256 * 4);
    ushort* Wt1      = (ushort*)carve((size_t)256 * 256 * 2);
    ushort* Wt2      = (ushort*)carve((size_t)256 * 512 * 2);
    ushort* Wt3      = (ushort*)carve((size_t)128 * 256 * 2);
    ushort* cat1     = (ushort*)carve((size_t)N * 256 * 2);   // [agg(x)|xb] bf16
    unsigned char* xq  = (unsigned char*)carve((size_t)N * 128);  // x fp8
    unsigned char* h1q = (unsigned char*)carve((size_t)N * 256);  // h1 fp8
    ushort* cat2     = (ushort*)carve((size_t)N * 512 * 2);   // [agg(h1)|h1]; later h2b
    ushort* zb       = (ushort*)carve((size_t)N * HID * 2);   // bf16 z1/z2
    unsigned char* p3q = (unsigned char*)carve((size_t)N * 64);   // p3 fp8
    float*  q3       = (float*)carve((size_t)N * 48 * 4);
    (void)ws_size; (void)n_in; (void)out_size;

    hipMemsetAsync(gcnt, 0, 256 * 4, stream);
    hipMemsetAsync(Wt3, 0, (size_t)128 * 256 * 2, stream);

    int bktB = (E + 8191) / 8192;
    int cvtB = (N * 128 + 255) / 256;
    k_pre<<<bktB + cvtB + 256, 256, 0, stream>>>(dst, E, gcnt, x, cat1, xq, N * 128,
                                                 w1l, w1r, w2l, w2r, w3l, w3r,
                                                 Wt1, Wt2, Wt3, bktB, cvtB);
    k_bscan<<<1, 256, 0, stream>>>(gcnt, gbase, gtail, NB);
    k_scatter<<<bktB, 256, 0, stream>>>(src, dst, E, gtail, pairs, NB);
    k_brow<<<NB, 256, 0, stream>>>(pairs, gbase, gcnt, row_ptr, inv_deg, N, E);
    k_bfill<<<NB, 256, 0, stream>>>(pairs, gbase, gcnt, row_ptr, colidx, N);

    int aggBlocks = (N + 3) / 4;
    int MB = (N + 63) / 64;   // 64-row tiles (782)
    long total8 = (long)N * 32;
    ushort* h2b = cat2;  // reuse

    // ---- layer 1 ----
    k_agg128q<<<aggBlocks, 256, 0, stream>>>(xq, row_ptr, colidx, inv_deg, cat1, 256, N);
    k_mgemm<2><<<MB * 2, 256, 0, stream>>>(cat1, Wt1, b1, zb, nullptr, nullptr,
                                           psum, psq, N, 256, 256);
    k_bn_final<<<256, 256, 0, stream>>>(psum, psq, MB, N, g1, be1, bnscale, bnshift);
    k_bn_apply_b<<<1024, 256, 0, stream>>>(zb, total8, bnscale, bnshift, cat2, 512, 256, h1q);

    // ---- layer 2 ----
    k_agg256q<<<aggBlocks, 256, 0, stream>>>(h1q, row_ptr, colidx, inv_deg, cat2, 512, N);
    k_mgemm<2><<<MB * 2, 256, 0, stream>>>(cat2, Wt2, b2, zb, nullptr, nullptr,
                                           psum, psq, N, 512, 256);
    k_bn_final<<<256, 256, 0, stream>>>(psum, psq, MB, N, g2, be2, bnscale, bnshift);
    k_bn_apply_b<<<1024, 256, 0, stream>>>(zb, total8, bnscale, bnshift, h2b, 256, 0, nullptr);

    // ---- layer 3: fp8 p3 / f32 q3 epilogue, then fused agg + log_softmax ----
    k_mgemm<1><<<MB, 256, 0, stream>>>(h2b, Wt3, b3, nullptr, p3q, q3,
                                       nullptr, nullptr, N, 256, 128);
    k_agg47fq<<<aggBlocks, 256, 0, stream>>>(p3q, row_ptr, colidx, inv_deg, q3, out, N, OUTD);
}